// Round 4
// baseline (970.390 us; speedup 1.0000x reference)
//
#include <hip/hip_runtime.h>
#include <hip/hip_bf16.h>
#include <cstdio>

typedef unsigned short ushort_t;
using bf16x8  = __attribute__((ext_vector_type(8))) __bf16;
using floatx4 = __attribute__((ext_vector_type(4))) float;

// Problem constants
constexpr int    kTokens = 50176;                       // B*nW*N = 16*64*49
constexpr size_t TCsz    = (size_t)kTokens * 256;       // 12,845,056 elements
constexpr float  kScale  = 0.17677669529663687f;        // 32^-0.5
constexpr int    SPITCH  = 56;                          // bias table row pitch
constexpr size_t SPAIR   = 49 * 56;                     // 2744
constexpr size_t VTP     = 2048;                        // V^T per pair: 32 d x 64 n
constexpr size_t VTSZ    = (size_t)8192 * VTP;          // 16,777,216 halves per branch

__device__ __forceinline__ float bf2f(ushort_t u) {
  unsigned int x = (unsigned int)u << 16;
  return __uint_as_float(x);
}
__device__ __forceinline__ ushort_t f2bf(float f) {
  __hip_bfloat16 h = __float2bfloat16(f);
  return *(ushort_t*)&h;
}

// async global->LDS 16B per lane: LDS dest = wave-uniform base + lane*16
__device__ __forceinline__ void gl_lds16(const ushort_t* g, ushort_t* l) {
  __builtin_amdgcn_global_load_lds(
      (const __attribute__((address_space(1))) unsigned int*)g,
      (__attribute__((address_space(3))) unsigned int*)l, 16, 0, 0);
}

// ---------------- weight fp32 -> bf16 conversion ----------------
__global__ __launch_bounds__(256) void f2b_k(const float* __restrict__ src,
                                             ushort_t* __restrict__ dst, int n) {
  int i = blockIdx.x * 256 + threadIdx.x;
  if (i < n) dst[i] = f2bf(src[i]);
}

// ---------------- precompute rpb + shift-mask bias table ----------------
// bias[cls][head][i][j], cls = (wh==7?2:0)+(ww==7?1:0), 49x56 tile (pad cols = 0)
__global__ __launch_bounds__(256) void bias_k(const float* __restrict__ rpb,
                                              float* __restrict__ bias) {
  const int cls = blockIdx.x >> 3, head = blockIdx.x & 7;
  const int wh7 = cls >> 1, ww7 = cls & 1;
  float* bp = bias + (size_t)blockIdx.x * SPAIR;
  for (int e = threadIdx.x; e < (int)SPAIR; e += 256) {
    const int i = e / SPITCH, j = e % SPITCH;
    float val = 0.0f;
    if (j < 49) {
      const int yi = i / 7, xi = i % 7, yj = j / 7, xj = j % 7;
      val = rpb[((yi - yj + 6) * 13 + (xi - xj + 6)) * 8 + head];
      const int li = (wh7 ? (yi < 4 ? 1 : 2) : 0) * 3 + (ww7 ? (xi < 4 ? 1 : 2) : 0);
      const int lj = (wh7 ? (yj < 4 ? 1 : 2) : 0) * 3 + (ww7 ? (xj < 4 ? 1 : 2) : 0);
      if (li != lj) val -= 100.0f;
    }
    bp[e] = val;
  }
}

// ---------------- zero V^T n-tail [48,64) (NaN guard for PV K-tail) ----------------
__global__ __launch_bounds__(256) void vtz_k(ushort_t* __restrict__ vtA,
                                             ushort_t* __restrict__ vtB) {
  const int id = blockIdx.x * 256 + threadIdx.x;       // 524288 threads
  ushort_t* base = (id < 262144) ? vtA : vtB;
  const size_t r = (size_t)(id & 262143) * 64;
  const uint4 z{0, 0, 0, 0};
  *(uint4*)(base + r + 48) = z;
  *(uint4*)(base + r + 56) = z;
}

// ---------------- LN (wave per token) + optional roll/window scatter -> bf16 ----------------
template <int SHIFTED>
__global__ __launch_bounds__(256) void ln_k(const float* __restrict__ x,
                                            const float* __restrict__ g,
                                            const float* __restrict__ b,
                                            ushort_t* __restrict__ yout) {
  const int wave = threadIdx.x >> 6, lane = threadIdx.x & 63;
  const int t = blockIdx.x * 4 + wave;
  size_t src;
  if (SHIFTED) {
    int bb = t / 3136, r = t % 3136;
    int wi = r / 49, n = r % 49;
    int hp = (wi >> 3) * 7 + n / 7;
    int wp = (wi & 7) * 7 + n % 7;
    int sh = hp + 3; if (sh >= 56) sh -= 56;
    int sw = wp + 3; if (sw >= 56) sw -= 56;
    src = ((size_t)bb * 3136 + sh * 56 + sw) * 256;
  } else {
    src = (size_t)t * 256;
  }
  const float4 v4 = *(const float4*)(x + src + lane * 4);
  float s  = v4.x + v4.y + v4.z + v4.w;
  float s2 = v4.x * v4.x + v4.y * v4.y + v4.z * v4.z + v4.w * v4.w;
#pragma unroll
  for (int off = 32; off > 0; off >>= 1) {
    s  += __shfl_xor(s,  off);
    s2 += __shfl_xor(s2, off);
  }
  const float mean = s * (1.0f / 256.0f);
  const float var  = s2 * (1.0f / 256.0f) - mean * mean;
  const float rstd = rsqrtf(var + 1e-5f);
  const float4 g4 = *(const float4*)(g + lane * 4);
  const float4 b4 = *(const float4*)(b + lane * 4);
  ushort4 o;
  o.x = f2bf((v4.x - mean) * rstd * g4.x + b4.x);
  o.y = f2bf((v4.y - mean) * rstd * g4.y + b4.y);
  o.z = f2bf((v4.z - mean) * rstd * g4.z + b4.z);
  o.w = f2bf((v4.w - mean) * rstd * g4.w + b4.w);
  *(ushort4*)(yout + (size_t)t * 256 + lane * 4) = o;
}

// ---------------- bf16 MFMA GEMM: out = A(M x K,bf16) @ W(N x K,bf16)^T ----------------
// 128x128 tile, BK=32, 4 waves. global_load_lds staging (linear LDS dest,
// inverse-XOR-swizzled source); XOR-swizzled ds_read_b128. XCD chunk swizzle.
// MODE 0: qkv scatter (+bias, q*scale); q,k -> [pair][n][d]; V -> transposed
//         [pair][d][64] (vt base passed via outf)
// MODE 1: proj: +bias, window-reverse+roll(+3) scatter, += aux -> fp32
// MODE 2: fc1: +bias, exact GELU -> bf16 [row*Nc+col]
// MODE 3: fc2: +bias, += aux -> fp32 [row*256+col]
template <int MODE>
__global__ __launch_bounds__(256) void bgemm_k(const ushort_t* __restrict__ A,
                                               const ushort_t* __restrict__ W,
                                               const float* __restrict__ bias,
                                               float* __restrict__ outf,
                                               ushort_t* __restrict__ outb,
                                               const float* __restrict__ aux,
                                               int K, int Nc) {
  __shared__ __align__(16) ushort_t As[128 * 32];
  __shared__ __align__(16) ushort_t Bs[128 * 32];
  const int tid = threadIdx.x;
  const int nbx = gridDim.x;
  const int nwg = nbx * gridDim.y;
  int flat = blockIdx.y * nbx + blockIdx.x;
  {
    const int xcd = flat & 7, idx = flat >> 3;
    const int q8 = nwg >> 3, r8 = nwg & 7;
    flat = (xcd < r8 ? xcd * (q8 + 1) : r8 * (q8 + 1) + (xcd - r8) * q8) + idx;
  }
  const int m0 = (flat / nbx) * 128;
  const int n0 = (flat % nbx) * 128;
  const int lane = tid & 63, wv = tid >> 6;
  const int wm = (wv >> 1) * 64, wn = (wv & 1) * 64;
  const int l16 = lane & 15, quad = lane >> 4;

  const int srow = tid >> 2;
  const int gkc  = (tid & 3) ^ ((tid >> 3) & 3);
  const ushort_t* Ag0 = A + (size_t)(m0 + srow) * K + gkc * 8;
  const ushort_t* Ag1 = A + (size_t)(m0 + 64 + srow) * K + gkc * 8;
  const ushort_t* Wg0 = W + (size_t)(n0 + srow) * K + gkc * 8;
  const ushort_t* Wg1 = W + (size_t)(n0 + 64 + srow) * K + gkc * 8;
  ushort_t* AsW0 = As + wv * 512;
  ushort_t* AsW1 = As + 2048 + wv * 512;
  ushort_t* BsW0 = Bs + wv * 512;
  ushort_t* BsW1 = Bs + 2048 + wv * 512;

  const int kcq = quad ^ ((l16 >> 1) & 3);
  const int arA = (wm + l16) * 32 + kcq * 8;
  const int arB = (wn + l16) * 32 + kcq * 8;

  floatx4 acc[4][4] = {};
  for (int k0 = 0; k0 < K; k0 += 32) {
    gl_lds16(Ag0, AsW0);
    gl_lds16(Ag1, AsW1);
    gl_lds16(Wg0, BsW0);
    gl_lds16(Wg1, BsW1);
    Ag0 += 32; Ag1 += 32; Wg0 += 32; Wg1 += 32;
    __syncthreads();
    bf16x8 af[4], bfr[4];
#pragma unroll
    for (int t = 0; t < 4; ++t) {
      af[t]  = *(const bf16x8*)&As[arA + t * 512];
      bfr[t] = *(const bf16x8*)&Bs[arB + t * 512];
    }
#pragma unroll
    for (int mt = 0; mt < 4; ++mt)
#pragma unroll
      for (int nt = 0; nt < 4; ++nt)
        acc[mt][nt] = __builtin_amdgcn_mfma_f32_16x16x32_bf16(af[mt], bfr[nt], acc[mt][nt], 0, 0, 0);
    __syncthreads();
  }

  // C/D layout: col = lane&15, row = quad*4 + reg.
  if (MODE == 0) {
    int wis[16], ns[16];
#pragma unroll
    for (int mt = 0; mt < 4; ++mt) {
      int row = m0 + wm + mt * 16 + quad * 4;
      int wi = row / 49, n = row - wi * 49;
#pragma unroll
      for (int r = 0; r < 4; ++r) {
        wis[mt * 4 + r] = wi; ns[mt * 4 + r] = n;
        if (++n == 49) { n = 0; ++wi; }
      }
    }
    if (n0 < 512) {          // q,k: [pair][n][32]
      size_t rb[16];
#pragma unroll
      for (int i = 0; i < 16; ++i) rb[i] = (size_t)wis[i] * 12544 + (size_t)ns[i] * 32;
#pragma unroll
      for (int nt = 0; nt < 4; ++nt) {
        const int col = n0 + wn + nt * 16 + l16;
        const int which = col >> 8, head = (col >> 5) & 7, d = col & 31;
        const float bv = bias[col];
        const float sc = (which == 0) ? kScale : 1.0f;
        ushort_t* ob = outb + (size_t)which * TCsz + head * 1568 + d;
#pragma unroll
        for (int i = 0; i < 16; ++i)
          ob[rb[i]] = f2bf((acc[i >> 2][nt][i & 3] + bv) * sc);
      }
    } else {                 // v: transposed [pair][d][64]
      size_t rb[16];
#pragma unroll
      for (int i = 0; i < 16; ++i) rb[i] = (size_t)wis[i] * 16384 + (size_t)ns[i];
      ushort_t* vtb = (ushort_t*)outf;
#pragma unroll
      for (int nt = 0; nt < 4; ++nt) {
        const int col = n0 + wn + nt * 16 + l16;
        const int head = (col >> 5) & 7, d = col & 31;
        const float bv = bias[col];
        ushort_t* ob = vtb + head * 2048 + d * 64;
#pragma unroll
        for (int i = 0; i < 16; ++i)
          ob[rb[i]] = f2bf(acc[i >> 2][nt][i & 3] + bv);
      }
    }
  } else if (MODE == 1) {
    size_t rb[16];
#pragma unroll
    for (int mt = 0; mt < 4; ++mt) {
#pragma unroll
      for (int r = 0; r < 4; ++r) {
        const int row = m0 + wm + mt * 16 + quad * 4 + r;
        const int wi = row / 49, n = row - wi * 49;
        const int b = wi >> 6, wl = wi & 63;
        int h = (wl >> 3) * 7 + n / 7 + 3; if (h >= 56) h -= 56;
        int w = (wl & 7) * 7 + n % 7 + 3; if (w >= 56) w -= 56;
        rb[mt * 4 + r] = ((size_t)(b * 3136 + h * 56 + w)) * 256;
      }
    }
#pragma unroll
    for (int nt = 0; nt < 4; ++nt) {
      const int col = n0 + wn + nt * 16 + l16;
      const float bv = bias[col];
#pragma unroll
      for (int i = 0; i < 16; ++i) {
        const size_t idx = rb[i] + col;
        outf[idx] = aux[idx] + acc[i >> 2][nt][i & 3] + bv;
      }
    }
  } else if (MODE == 2) {
    size_t rb[16];
#pragma unroll
    for (int mt = 0; mt < 4; ++mt)
#pragma unroll
      for (int r = 0; r < 4; ++r)
        rb[mt * 4 + r] = (size_t)(m0 + wm + mt * 16 + quad * 4 + r) * Nc;
#pragma unroll
    for (int nt = 0; nt < 4; ++nt) {
      const int col = n0 + wn + nt * 16 + l16;
      const float bv = bias[col];
#pragma unroll
      for (int i = 0; i < 16; ++i) {
        float val = acc[i >> 2][nt][i & 3] + bv;
        val = 0.5f * val * (1.0f + erff(val * 0.70710678118654752f));
        outb[rb[i] + col] = f2bf(val);
      }
    }
  } else {
    size_t rb[16];
#pragma unroll
    for (int mt = 0; mt < 4; ++mt)
#pragma unroll
      for (int r = 0; r < 4; ++r)
        rb[mt * 4 + r] = (size_t)(m0 + wm + mt * 16 + quad * 4 + r) * 256;
#pragma unroll
    for (int nt = 0; nt < 4; ++nt) {
      const int col = n0 + wn + nt * 16 + l16;
      const float bv = bias[col];
#pragma unroll
      for (int i = 0; i < 16; ++i) {
        const size_t idx = rb[i] + col;
        outf[idx] = aux[idx] + acc[i >> 2][nt][i & 3] + bv;
      }
    }
  }
}

// ---------------- fused attention: scores(MFMA) + bias + gate + softmax + PV(MFMA) ----
// block = (window, 16-row chunk); 4096 blocks, 256 threads (4 waves, 4 pairs/wave).
// S in LDS bf16 [16 pairs][16 rows][56]; V^T read from global [pair][32][64].
__global__ __launch_bounds__(256) void attn_k(const ushort_t* __restrict__ qA,
                                              const ushort_t* __restrict__ qB,
                                              const ushort_t* __restrict__ vtA,
                                              const ushort_t* __restrict__ vtB,
                                              const float* __restrict__ bias,
                                              const float* __restrict__ fw,
                                              const float* __restrict__ fb,
                                              ushort_t* __restrict__ Obase) {
  __shared__ __align__(16) ushort_t S[16 * 16 * 56 + 64];
  __shared__ float fwl[64], fbl[8];
  const int tid = threadIdx.x, lane = tid & 63, wv = tid >> 6;
  const int l16 = lane & 15, quad = lane >> 4;
  int bx = blockIdx.x;
  bx = (bx & 7) * 512 + (bx >> 3);        // XCD chunk swizzle (4096 = 8*512)
  const int win = bx >> 2, chunk = bx & 3;
  const int r0 = chunk * 16;
  const int rows = (r0 + 16 <= 49) ? 16 : (49 - r0);
  // zero S (incl. pad) so unwritten rows read as 0 in PV
  {
    uint4* p4 = (uint4*)S;
    for (int i = tid; i < 1800; i += 256) p4[i] = uint4{0, 0, 0, 0};
  }
  if (tid < 64) fwl[tid] = fw[tid];
  if (tid < 8)  fbl[tid] = fb[tid];
  __syncthreads();

  const int wl = win & 63;
  const int cls = (((wl >> 3) == 7) ? 2 : 0) + (((wl & 7) == 7) ? 1 : 0);

  // ---- scores: 4 pairs per wave, K=32 single MFMA step ----
  // q-row and k-row clamped to 48 (duplicates row 48; results masked at store)
  const int qrow = (r0 + l16 <= 48) ? (r0 + l16) : 48;
  for (int i = 0; i < 4; ++i) {
    const int pair = wv * 4 + i;
    const int br = pair >> 3, h = pair & 7;
    const ushort_t* qb = (br ? qB : qA) + (size_t)(win * 8 + h) * 1568;
    const ushort_t* kb = qb + TCsz;
    const bf16x8 af = *(const bf16x8*)(qb + qrow * 32 + quad * 8);
    floatx4 acc[4];
#pragma unroll
    for (int nt = 0; nt < 4; ++nt) {
      const int krow = nt * 16 + l16;
      const int krc = (krow <= 48) ? krow : 48;
      const bf16x8 bfr = *(const bf16x8*)(kb + krc * 32 + quad * 8);
      acc[nt] = __builtin_amdgcn_mfma_f32_16x16x32_bf16(af, bfr, (floatx4){0.f, 0.f, 0.f, 0.f}, 0, 0, 0);
    }
    const float* bp = bias + (size_t)(cls * 8 + h) * SPAIR;
    ushort_t* Sp = S + pair * 896;
#pragma unroll
    for (int nt = 0; nt < 4; ++nt) {
      const int col = nt * 16 + l16;
      if (col >= SPITCH) continue;
#pragma unroll
      for (int r = 0; r < 4; ++r) {
        const int lrow = quad * 4 + r;
        if (lrow < rows)
          Sp[lrow * 56 + col] = (col < 49) ? f2bf(acc[nt][r] + bp[(r0 + lrow) * 56 + col]) : (ushort_t)0;
      }
    }
  }
  __syncthreads();

  // ---- gate: s_A <- s_A + d * sigmoid(fw @ d + fb) ----
  const int np = rows * 49;
  for (int p = tid; p < np; p += 256) {
    const int lr = p / 49, c = p - lr * 49;
    const int off = lr * 56 + c;
    float sA[8], dd[8];
#pragma unroll
    for (int h = 0; h < 8; ++h) {
      sA[h] = bf2f(S[h * 896 + off]);
      dd[h] = bf2f(S[(8 + h) * 896 + off]) - sA[h];
    }
#pragma unroll
    for (int o = 0; o < 8; ++o) {
      float g = fbl[o];
#pragma unroll
      for (int h = 0; h < 8; ++h) g = fmaf(fwl[o * 8 + h], dd[h], g);
      g = __builtin_amdgcn_rcpf(1.0f + __expf(-g));
      S[o * 896 + off] = f2bf(sA[o] + dd[o] * g);
    }
  }
  __syncthreads();

  // ---- softmax: one thread per (pair, row) = 256 threads exactly ----
  {
    const int lr = tid & 15, ph = tid >> 4;
    if (lr < rows) {
      ushort_t* row = S + ph * 896 + lr * 56;
      float mx = -1e30f;
      for (int m = 0; m < 49; ++m) mx = fmaxf(mx, bf2f(row[m]));
      float sum = 0.0f;
      for (int m = 0; m < 49; ++m) sum += __expf(bf2f(row[m]) - mx);
      const float inv = __builtin_amdgcn_rcpf(sum);
      for (int m = 0; m < 49; ++m) row[m] = f2bf(__expf(bf2f(row[m]) - mx) * inv);
    }
  }
  __syncthreads();

  // ---- PV: O[n][d] = sum_m P[n][m] V[m][d]; V^T zero-padded m in [49,64) ----
  for (int i = 0; i < 4; ++i) {
    const int pair = wv * 4 + i;
    const int br = pair >> 3, h = pair & 7;
    const ushort_t* vt = (br ? vtB : vtA) + (size_t)(win * 8 + h) * VTP;
    const ushort_t* Sp = S + pair * 896;
    floatx4 acc[2] = {};
#pragma unroll
    for (int ks = 0; ks < 2; ++ks) {
      const bf16x8 af = *(const bf16x8*)(Sp + l16 * 56 + ks * 32 + quad * 8);
#pragma unroll
      for (int nt = 0; nt < 2; ++nt) {
        const bf16x8 bv = *(const bf16x8*)(vt + (nt * 16 + l16) * 64 + ks * 32 + quad * 8);
        acc[nt] = __builtin_amdgcn_mfma_f32_16x16x32_bf16(af, bv, acc[nt], 0, 0, 0);
      }
    }
    ushort_t* Ob = Obase + (size_t)br * TCsz + (size_t)(win * 49 + r0) * 256 + h * 32;
#pragma unroll
    for (int nt = 0; nt < 2; ++nt)
#pragma unroll
      for (int r = 0; r < 4; ++r) {
        const int n = quad * 4 + r;
        if (n < rows) Ob[(size_t)n * 256 + nt * 16 + l16] = f2bf(acc[nt][r]);
      }
  }
}

extern "C" void kernel_launch(void* const* d_in, const int* in_sizes, int n_in,
                              void* d_out, int out_size, void* d_ws, size_t ws_size,
                              hipStream_t stream) {
  if (n_in < 29) { fprintf(stderr, "kernel_launch: expected 29 inputs, got %d\n", n_in); return; }
  const float* x      = (const float*)d_in[0];
  const float* xsar   = (const float*)d_in[1];
  const float* ln1_g  = (const float*)d_in[2];
  const float* ln1_b  = (const float*)d_in[3];
  const float* ln1s_g = (const float*)d_in[4];
  const float* ln1s_b = (const float*)d_in[5];
  const float* qkv_w  = (const float*)d_in[6];
  const float* qkv_b  = (const float*)d_in[7];
  const float* qkvs_w = (const float*)d_in[8];
  const float* qkvs_b = (const float*)d_in[9];
  const float* rpb    = (const float*)d_in[10];
  const float* fuse_w = (const float*)d_in[11];
  const float* fuse_b = (const float*)d_in[12];
  const float* proj_w = (const float*)d_in[13];
  const float* proj_b = (const float*)d_in[14];
  const float* projs_w = (const float*)d_in[15];
  const float* projs_b = (const float*)d_in[16];
  const float* ln2_g  = (const float*)d_in[17];
  const float* ln2_b  = (const float*)d_in[18];
  const float* ln2s_g = (const float*)d_in[19];
  const float* ln2s_b = (const float*)d_in[20];
  const float* fc1_w  = (const float*)d_in[21];
  const float* fc1_b  = (const float*)d_in[22];
  const float* fc2_w  = (const float*)d_in[23];
  const float* fc2_b  = (const float*)d_in[24];
  const float* fc1s_w = (const float*)d_in[25];
  const float* fc1s_b = (const float*)d_in[26];
  const float* fc2s_w = (const float*)d_in[27];
  const float* fc2s_b = (const float*)d_in[28];
  float* out = (float*)d_out;
  float* ws  = (float*)d_ws;

  const size_t need = 8 * TCsz * sizeof(float);
  if (ws_size < need) {
    fprintf(stderr, "kernel_launch: ws_size %zu < needed %zu\n", ws_size, need);
    return;
  }

  // --- workspace map (halves H) ---
  // xw[0,1TC) xws[1,2TC) | q[2,3) k[3,4) qs[5,6) ks[6,7) | VT_A/VT_B at [8TC,..)
  // O->xw slot, Os->xws, y->q, ys->k, hbuf->[4,8TC) | xr fp32 [6,7)f xrs [7,8)f
  ushort_t* H   = (ushort_t*)ws;
  ushort_t* xw  = H;
  ushort_t* xws = H + TCsz;
  ushort_t* q   = H + 2 * TCsz;   // q; k at +TCsz
  ushort_t* qs  = H + 5 * TCsz;   // qs; ks at +TCsz
  ushort_t* vtA = H + 8 * TCsz;
  ushort_t* vtB = vtA + VTSZ;
  float* xr  = ws + 6 * TCsz;
  float* xrs = ws + 7 * TCsz;
  ushort_t* y   = H + 2 * TCsz;
  ushort_t* ysb = H + 3 * TCsz;
  ushort_t* hbuf = H + 4 * TCsz;  // 4 TC halves: full M x 1024
  ushort_t* wb  = H + 12 * TCsz - 1572864;  // bf16 weights, below xr region
  float* biasbuf = (float*)(H + 12 * TCsz - 1572864 - 175616);  // 4*8*2744 fp32
  ushort_t* wqkv  = wb;
  ushort_t* wqkvs = wb + 196608;
  ushort_t* wproj = wb + 393216;
  ushort_t* wprojs= wb + 458752;
  ushort_t* wfc1  = wb + 524288;
  ushort_t* wfc1s = wb + 786432;
  ushort_t* wfc2  = wb + 1048576;
  ushort_t* wfc2s = wb + 1310720;

  // 0. convert weights + bias table + V^T tail zero
  f2b_k<<<768, 256, 0, stream>>>(qkv_w,  wqkv,  196608);
  f2b_k<<<768, 256, 0, stream>>>(qkvs_w, wqkvs, 196608);
  f2b_k<<<256, 256, 0, stream>>>(proj_w, wproj, 65536);
  f2b_k<<<256, 256, 0, stream>>>(projs_w,wprojs,65536);
  f2b_k<<<1024,256, 0, stream>>>(fc1_w,  wfc1,  262144);
  f2b_k<<<1024,256, 0, stream>>>(fc1s_w, wfc1s, 262144);
  f2b_k<<<1024,256, 0, stream>>>(fc2_w,  wfc2,  262144);
  f2b_k<<<1024,256, 0, stream>>>(fc2s_w, wfc2s, 262144);
  bias_k<<<32, 256, 0, stream>>>(rpb, biasbuf);
  vtz_k<<<2048, 256, 0, stream>>>(vtA, vtB);

  // 1. LN1 + shift + window partition (bf16 out)
  ln_k<1><<<12544, 256, 0, stream>>>(x,    ln1_g,  ln1_b,  xw);
  ln_k<1><<<12544, 256, 0, stream>>>(xsar, ln1s_g, ln1s_b, xws);
  // 2. QKV MFMA GEMM (q pre-scaled); q,k -> [pair][n][d], V -> [pair][d][64]
  bgemm_k<0><<<dim3(6, 392), 256, 0, stream>>>(xw,  wqkv,  qkv_b,  (float*)vtA, q,  nullptr, 256, 768);
  bgemm_k<0><<<dim3(6, 392), 256, 0, stream>>>(xws, wqkvs, qkvs_b, (float*)vtB, qs, nullptr, 256, 768);
  // 3. fused attention (scores + gate + softmax + PV), both branches
  attn_k<<<4096, 256, 0, stream>>>(q, qs, vtA, vtB, biasbuf, fuse_w, fuse_b, H);
  // 4. proj MFMA + window-reverse + roll(+3) + residual -> fp32 xr
  bgemm_k<1><<<dim3(2, 392), 256, 0, stream>>>(H,        wproj,  proj_b,  xr,  nullptr, x,    256, 256);
  bgemm_k<1><<<dim3(2, 392), 256, 0, stream>>>(H + TCsz, wprojs, projs_b, xrs, nullptr, xsar, 256, 256);
  // 5. LN2 (bf16 out)
  ln_k<0><<<12544, 256, 0, stream>>>(xr,  ln2_g,  ln2_b,  y);
  ln_k<0><<<12544, 256, 0, stream>>>(xrs, ln2s_g, ln2s_b, ysb);
  // 6. MLP (MFMA)
  bgemm_k<2><<<dim3(8, 392), 256, 0, stream>>>(y,    wfc1,  fc1_b,  nullptr, hbuf, nullptr, 256, 1024);
  bgemm_k<3><<<dim3(2, 392), 256, 0, stream>>>(hbuf, wfc2,  fc2_b,  out,     nullptr, xr,  1024, 256);
  bgemm_k<2><<<dim3(8, 392), 256, 0, stream>>>(ysb,  wfc1s, fc1s_b, nullptr, hbuf, nullptr, 256, 1024);
  bgemm_k<3><<<dim3(2, 392), 256, 0, stream>>>(hbuf, wfc2s, fc2s_b, out + TCsz, nullptr, xrs, 1024, 256);
}

// Round 5
// 937.918 us; speedup vs baseline: 1.0346x; 1.0346x over previous
//
#include <hip/hip_runtime.h>
#include <hip/hip_bf16.h>
#include <cstdio>

typedef unsigned short ushort_t;
using bf16x8  = __attribute__((ext_vector_type(8))) __bf16;
using u16x8   = __attribute__((ext_vector_type(8))) unsigned short;
using floatx4 = __attribute__((ext_vector_type(4))) float;

// Problem constants
constexpr int    kTokens = 50176;                       // B*nW*N = 16*64*49
constexpr size_t TCsz    = (size_t)kTokens * 256;       // 12,845,056 elements
constexpr float  kScale  = 0.17677669529663687f;        // 32^-0.5
constexpr int    SPITCH  = 56;                          // S row pitch (halves)
constexpr size_t VTP     = 2048;                        // V^T per pair: 32 d x 64 n
constexpr size_t VTSZ    = (size_t)8192 * VTP;          // halves per branch

__device__ __forceinline__ float bf2f(ushort_t u) {
  unsigned int x = (unsigned int)u << 16;
  return __uint_as_float(x);
}
__device__ __forceinline__ ushort_t f2bf(float f) {
  __hip_bfloat16 h = __float2bfloat16(f);
  return *(ushort_t*)&h;
}

// async global->LDS 16B per lane: LDS dest = wave-uniform base + lane*16
__device__ __forceinline__ void gl_lds16(const ushort_t* g, ushort_t* l) {
  __builtin_amdgcn_global_load_lds(
      (const __attribute__((address_space(1))) unsigned int*)g,
      (__attribute__((address_space(3))) unsigned int*)l, 16, 0, 0);
}

// ---------------- weight fp32 -> bf16 conversion ----------------
__global__ __launch_bounds__(256) void f2b_k(const float* __restrict__ src,
                                             ushort_t* __restrict__ dst, int n) {
  int i = blockIdx.x * 256 + threadIdx.x;
  if (i < n) dst[i] = f2bf(src[i]);
}

// ---------------- precompute rpb + shift-mask bias in MFMA C/D FRAGMENT layout ------
// biasf[((cls*4+chunk)*8+head)*64 + lane][nt*4+r] fp32; 128 blocks x 64 threads.
// value = rpb+mask at (row = chunk*16 + (lane>>4)*4 + r, col = nt*16 + (lane&15)).
__global__ __launch_bounds__(64) void bias2_k(const float* __restrict__ rpb,
                                              float* __restrict__ biasf) {
  const int b = blockIdx.x;                 // ((cls*4+chunk)*8+head)
  const int head = b & 7, chunk = (b >> 3) & 3, cls = b >> 5;
  const int wh7 = cls >> 1, ww7 = cls & 1;
  const int lane = threadIdx.x;
  float* bp = biasf + ((size_t)b * 64 + lane) * 16;
#pragma unroll
  for (int nt = 0; nt < 4; ++nt) {
#pragma unroll
    for (int r = 0; r < 4; ++r) {
      const int row = chunk * 16 + (lane >> 4) * 4 + r;
      const int col = nt * 16 + (lane & 15);
      float val = 0.0f;
      if (row < 49 && col < 49) {
        const int yi = row / 7, xi = row % 7, yj = col / 7, xj = col % 7;
        val = rpb[((yi - yj + 6) * 13 + (xi - xj + 6)) * 8 + head];
        const int li = (wh7 ? (yi < 4 ? 1 : 2) : 0) * 3 + (ww7 ? (xi < 4 ? 1 : 2) : 0);
        const int lj = (wh7 ? (yj < 4 ? 1 : 2) : 0) * 3 + (ww7 ? (xj < 4 ? 1 : 2) : 0);
        if (li != lj) val -= 100.0f;
      }
      bp[nt * 4 + r] = val;
    }
  }
}

// ---------------- zero V^T n-tail [48,64) (NaN guard for PV K-tail) ----------------
__global__ __launch_bounds__(256) void vtz_k(ushort_t* __restrict__ vtA,
                                             ushort_t* __restrict__ vtB) {
  const int id = blockIdx.x * 256 + threadIdx.x;       // 524288 threads
  ushort_t* base = (id < 262144) ? vtA : vtB;
  const size_t r = (size_t)(id & 262143) * 64;
  const uint4 z{0, 0, 0, 0};
  *(uint4*)(base + r + 48) = z;
  *(uint4*)(base + r + 56) = z;
}

// ---------------- LN (wave per token) + optional roll/window scatter -> bf16 ----------------
template <int SHIFTED>
__global__ __launch_bounds__(256) void ln_k(const float* __restrict__ x,
                                            const float* __restrict__ g,
                                            const float* __restrict__ b,
                                            ushort_t* __restrict__ yout) {
  const int wave = threadIdx.x >> 6, lane = threadIdx.x & 63;
  const int t = blockIdx.x * 4 + wave;
  size_t src;
  if (SHIFTED) {
    int bb = t / 3136, r = t % 3136;
    int wi = r / 49, n = r % 49;
    int hp = (wi >> 3) * 7 + n / 7;
    int wp = (wi & 7) * 7 + n % 7;
    int sh = hp + 3; if (sh >= 56) sh -= 56;
    int sw = wp + 3; if (sw >= 56) sw -= 56;
    src = ((size_t)bb * 3136 + sh * 56 + sw) * 256;
  } else {
    src = (size_t)t * 256;
  }
  const float4 v4 = *(const float4*)(x + src + lane * 4);
  float s  = v4.x + v4.y + v4.z + v4.w;
  float s2 = v4.x * v4.x + v4.y * v4.y + v4.z * v4.z + v4.w * v4.w;
#pragma unroll
  for (int off = 32; off > 0; off >>= 1) {
    s  += __shfl_xor(s,  off);
    s2 += __shfl_xor(s2, off);
  }
  const float mean = s * (1.0f / 256.0f);
  const float var  = s2 * (1.0f / 256.0f) - mean * mean;
  const float rstd = rsqrtf(var + 1e-5f);
  const float4 g4 = *(const float4*)(g + lane * 4);
  const float4 b4 = *(const float4*)(b + lane * 4);
  ushort4 o;
  o.x = f2bf((v4.x - mean) * rstd * g4.x + b4.x);
  o.y = f2bf((v4.y - mean) * rstd * g4.y + b4.y);
  o.z = f2bf((v4.z - mean) * rstd * g4.z + b4.z);
  o.w = f2bf((v4.w - mean) * rstd * g4.w + b4.w);
  *(ushort4*)(yout + (size_t)t * 256 + lane * 4) = o;
}

// ---------------- bf16 MFMA GEMM: out = A(M x K,bf16) @ W(N x K,bf16)^T ----------------
template <int MODE>
__global__ __launch_bounds__(256) void bgemm_k(const ushort_t* __restrict__ A,
                                               const ushort_t* __restrict__ W,
                                               const float* __restrict__ bias,
                                               float* __restrict__ outf,
                                               ushort_t* __restrict__ outb,
                                               const float* __restrict__ aux,
                                               int K, int Nc) {
  __shared__ __align__(16) ushort_t As[128 * 32];
  __shared__ __align__(16) ushort_t Bs[128 * 32];
  const int tid = threadIdx.x;
  const int nbx = gridDim.x;
  const int nwg = nbx * gridDim.y;
  int flat = blockIdx.y * nbx + blockIdx.x;
  {
    const int xcd = flat & 7, idx = flat >> 3;
    const int q8 = nwg >> 3, r8 = nwg & 7;
    flat = (xcd < r8 ? xcd * (q8 + 1) : r8 * (q8 + 1) + (xcd - r8) * q8) + idx;
  }
  const int m0 = (flat / nbx) * 128;
  const int n0 = (flat % nbx) * 128;
  const int lane = tid & 63, wv = tid >> 6;
  const int wm = (wv >> 1) * 64, wn = (wv & 1) * 64;
  const int l16 = lane & 15, quad = lane >> 4;

  const int srow = tid >> 2;
  const int gkc  = (tid & 3) ^ ((tid >> 3) & 3);
  const ushort_t* Ag0 = A + (size_t)(m0 + srow) * K + gkc * 8;
  const ushort_t* Ag1 = A + (size_t)(m0 + 64 + srow) * K + gkc * 8;
  const ushort_t* Wg0 = W + (size_t)(n0 + srow) * K + gkc * 8;
  const ushort_t* Wg1 = W + (size_t)(n0 + 64 + srow) * K + gkc * 8;
  ushort_t* AsW0 = As + wv * 512;
  ushort_t* AsW1 = As + 2048 + wv * 512;
  ushort_t* BsW0 = Bs + wv * 512;
  ushort_t* BsW1 = Bs + 2048 + wv * 512;

  const int kcq = quad ^ ((l16 >> 1) & 3);
  const int arA = (wm + l16) * 32 + kcq * 8;
  const int arB = (wn + l16) * 32 + kcq * 8;

  floatx4 acc[4][4] = {};
  for (int k0 = 0; k0 < K; k0 += 32) {
    gl_lds16(Ag0, AsW0);
    gl_lds16(Ag1, AsW1);
    gl_lds16(Wg0, BsW0);
    gl_lds16(Wg1, BsW1);
    Ag0 += 32; Ag1 += 32; Wg0 += 32; Wg1 += 32;
    __syncthreads();
    bf16x8 af[4], bfr[4];
#pragma unroll
    for (int t = 0; t < 4; ++t) {
      af[t]  = *(const bf16x8*)&As[arA + t * 512];
      bfr[t] = *(const bf16x8*)&Bs[arB + t * 512];
    }
#pragma unroll
    for (int mt = 0; mt < 4; ++mt)
#pragma unroll
      for (int nt = 0; nt < 4; ++nt)
        acc[mt][nt] = __builtin_amdgcn_mfma_f32_16x16x32_bf16(af[mt], bfr[nt], acc[mt][nt], 0, 0, 0);
    __syncthreads();
  }

  // C/D layout: col = lane&15, row = quad*4 + reg.
  if (MODE == 0) {
    int wis[16], ns[16];
#pragma unroll
    for (int mt = 0; mt < 4; ++mt) {
      int row = m0 + wm + mt * 16 + quad * 4;
      int wi = row / 49, n = row - wi * 49;
#pragma unroll
      for (int r = 0; r < 4; ++r) {
        wis[mt * 4 + r] = wi; ns[mt * 4 + r] = n;
        if (++n == 49) { n = 0; ++wi; }
      }
    }
    if (n0 < 512) {          // q,k: [pair][n][32]
      size_t rb[16];
#pragma unroll
      for (int i = 0; i < 16; ++i) rb[i] = (size_t)wis[i] * 12544 + (size_t)ns[i] * 32;
#pragma unroll
      for (int nt = 0; nt < 4; ++nt) {
        const int col = n0 + wn + nt * 16 + l16;
        const int which = col >> 8, head = (col >> 5) & 7, d = col & 31;
        const float bv = bias[col];
        const float sc = (which == 0) ? kScale : 1.0f;
        ushort_t* ob = outb + (size_t)which * TCsz + head * 1568 + d;
#pragma unroll
        for (int i = 0; i < 16; ++i)
          ob[rb[i]] = f2bf((acc[i >> 2][nt][i & 3] + bv) * sc);
      }
    } else {                 // v: transposed [pair][d][64]
      size_t rb[16];
#pragma unroll
      for (int i = 0; i < 16; ++i) rb[i] = (size_t)wis[i] * 16384 + (size_t)ns[i];
      ushort_t* vtb = (ushort_t*)outf;
#pragma unroll
      for (int nt = 0; nt < 4; ++nt) {
        const int col = n0 + wn + nt * 16 + l16;
        const int head = (col >> 5) & 7, d = col & 31;
        const float bv = bias[col];
        ushort_t* ob = vtb + head * 2048 + d * 64;
#pragma unroll
        for (int i = 0; i < 16; ++i)
          ob[rb[i]] = f2bf(acc[i >> 2][nt][i & 3] + bv);
      }
    }
  } else if (MODE == 1) {
    size_t rb[16];
#pragma unroll
    for (int mt = 0; mt < 4; ++mt) {
#pragma unroll
      for (int r = 0; r < 4; ++r) {
        const int row = m0 + wm + mt * 16 + quad * 4 + r;
        const int wi = row / 49, n = row - wi * 49;
        const int b = wi >> 6, wl = wi & 63;
        int h = (wl >> 3) * 7 + n / 7 + 3; if (h >= 56) h -= 56;
        int w = (wl & 7) * 7 + n % 7 + 3; if (w >= 56) w -= 56;
        rb[mt * 4 + r] = ((size_t)(b * 3136 + h * 56 + w)) * 256;
      }
    }
#pragma unroll
    for (int nt = 0; nt < 4; ++nt) {
      const int col = n0 + wn + nt * 16 + l16;
      const float bv = bias[col];
#pragma unroll
      for (int i = 0; i < 16; ++i) {
        const size_t idx = rb[i] + col;
        outf[idx] = aux[idx] + acc[i >> 2][nt][i & 3] + bv;
      }
    }
  } else if (MODE == 2) {
    size_t rb[16];
#pragma unroll
    for (int mt = 0; mt < 4; ++mt)
#pragma unroll
      for (int r = 0; r < 4; ++r)
        rb[mt * 4 + r] = (size_t)(m0 + wm + mt * 16 + quad * 4 + r) * Nc;
#pragma unroll
    for (int nt = 0; nt < 4; ++nt) {
      const int col = n0 + wn + nt * 16 + l16;
      const float bv = bias[col];
#pragma unroll
      for (int i = 0; i < 16; ++i) {
        float val = acc[i >> 2][nt][i & 3] + bv;
        val = 0.5f * val * (1.0f + erff(val * 0.70710678118654752f));
        outb[rb[i] + col] = f2bf(val);
      }
    }
  } else {
    size_t rb[16];
#pragma unroll
    for (int mt = 0; mt < 4; ++mt)
#pragma unroll
      for (int r = 0; r < 4; ++r)
        rb[mt * 4 + r] = (size_t)(m0 + wm + mt * 16 + quad * 4 + r) * 256;
#pragma unroll
    for (int nt = 0; nt < 4; ++nt) {
      const int col = n0 + wn + nt * 16 + l16;
      const float bv = bias[col];
#pragma unroll
      for (int i = 0; i < 16; ++i) {
        const size_t idx = rb[i] + col;
        outf[idx] = aux[idx] + acc[i >> 2][nt][i & 3] + bv;
      }
    }
  }
}

// ---------------- fused attention: scores(MFMA) + bias + gate + softmax + PV(MFMA) ----
// block = (window, 16-row chunk); 4096 blocks, 256 threads (4 waves, 4 pairs/wave).
// S in LDS bf16 [16 pairs][16 rows][56]; V^T from global [pair][32][64].
// Softmax leaves UNNORMALIZED exp in S; 1/sum applied in the PV epilogue.
__global__ __launch_bounds__(256) void attn_k(const ushort_t* __restrict__ qA,
                                              const ushort_t* __restrict__ qB,
                                              const ushort_t* __restrict__ vtA,
                                              const ushort_t* __restrict__ vtB,
                                              const float* __restrict__ biasf,
                                              const float* __restrict__ fw,
                                              const float* __restrict__ fb,
                                              ushort_t* __restrict__ Obase) {
  __shared__ __align__(16) ushort_t S[16 * 16 * 56 + 64];
  __shared__ float fwl[64], fbl[8];
  __shared__ float linv[256];
  const int tid = threadIdx.x, lane = tid & 63, wv = tid >> 6;
  const int l16 = lane & 15, quad = lane >> 4;
  int bx = blockIdx.x;
  bx = (bx & 7) * 512 + (bx >> 3);        // XCD chunk swizzle (4096 = 8*512)
  const int win = bx >> 2, chunk = bx & 3;
  const int r0 = chunk * 16;
  const int rows = (r0 + 16 <= 49) ? 16 : (49 - r0);

  // zero only tail rows (chunk 3) + guard region; scores writes all of rows<rows
  if (rows < 16) {
    const int per = (16 - rows) * 7;               // uint4 per pair
    for (int u = tid; u < 16 * per; u += 256) {
      const int pr = u / per, off = u - pr * per;
      *(uint4*)(S + pr * 896 + rows * 56 + off * 8) = uint4{0, 0, 0, 0};
    }
  }
  if (tid < 16) *(uint4*)(S + 14336 + tid * 8) = uint4{0, 0, 0, 0};  // guard
  if (tid < 64) fwl[tid] = fw[tid];
  if (tid < 8)  fbl[tid] = fb[tid];
  __syncthreads();

  const int wl = win & 63;
  const int cls = (((wl >> 3) == 7) ? 2 : 0) + (((wl & 7) == 7) ? 1 : 0);

  // ---- scores: 4 pairs per wave, K=32 single MFMA step; fragment-layout bias ----
  const int qrow = (r0 + l16 <= 48) ? (r0 + l16) : 48;
  for (int i = 0; i < 4; ++i) {
    const int pair = wv * 4 + i;
    const int br = pair >> 3, h = pair & 7;
    const ushort_t* qb = (br ? qB : qA) + (size_t)(win * 8 + h) * 1568;
    const ushort_t* kb = qb + TCsz;
    const bf16x8 af = *(const bf16x8*)(qb + qrow * 32 + quad * 8);
    floatx4 acc[4];
#pragma unroll
    for (int nt = 0; nt < 4; ++nt) {
      const int krow = nt * 16 + l16;
      const int krc = (krow <= 48) ? krow : 48;
      const bf16x8 bfr = *(const bf16x8*)(kb + krc * 32 + quad * 8);
      acc[nt] = __builtin_amdgcn_mfma_f32_16x16x32_bf16(af, bfr, (floatx4){0.f, 0.f, 0.f, 0.f}, 0, 0, 0);
    }
    const float* bfp = biasf + ((size_t)((cls * 4 + chunk) * 8 + h) * 64 + lane) * 16;
    ushort_t* Sp = S + pair * 896;
#pragma unroll
    for (int nt = 0; nt < 4; ++nt) {
      const int col = nt * 16 + l16;
      if (col >= SPITCH) continue;
      const float4 bv4 = *(const float4*)(bfp + nt * 4);
      const float bvv[4] = {bv4.x, bv4.y, bv4.z, bv4.w};
#pragma unroll
      for (int r = 0; r < 4; ++r) {
        const int lrow = quad * 4 + r;
        if (lrow < rows)
          Sp[lrow * 56 + col] = (col < 49) ? f2bf(acc[nt][r] + bvv[r]) : (ushort_t)0;
      }
    }
  }
  __syncthreads();

  // ---- gate: s_A <- s_A + d * sigmoid(fw @ d + fb) ----
  const int np = rows * 49;
  for (int p = tid; p < np; p += 256) {
    const int lr = p / 49, c = p - lr * 49;
    const int off = lr * 56 + c;
    float sA[8], dd[8];
#pragma unroll
    for (int h = 0; h < 8; ++h) {
      sA[h] = bf2f(S[h * 896 + off]);
      dd[h] = bf2f(S[(8 + h) * 896 + off]) - sA[h];
    }
#pragma unroll
    for (int o = 0; o < 8; ++o) {
      float g = fbl[o];
#pragma unroll
      for (int h = 0; h < 8; ++h) g = fmaf(fwl[o * 8 + h], dd[h], g);
      g = __builtin_amdgcn_rcpf(1.0f + __expf(-g));
      S[o * 896 + off] = f2bf(sA[o] + dd[o] * g);
    }
  }
  __syncthreads();

  // ---- softmax (vectorized, unnormalized): one thread per (pair, row) ----
  {
    const int lr = tid & 15, ph = tid >> 4;
    if (lr < rows) {
      ushort_t* row = S + ph * 896 + lr * 56;
      bf16x8 c[7];
#pragma unroll
      for (int j = 0; j < 7; ++j) c[j] = *(const bf16x8*)(row + j * 8);
      float mx = -1e30f;
#pragma unroll
      for (int j = 0; j < 6; ++j)
#pragma unroll
        for (int e = 0; e < 8; ++e) mx = fmaxf(mx, (float)c[j][e]);
      mx = fmaxf(mx, (float)c[6][0]);
      float sum = 0.0f;
#pragma unroll
      for (int j = 0; j < 6; ++j) {
        u16x8 o;
#pragma unroll
        for (int e = 0; e < 8; ++e) {
          const float ev = __expf((float)c[j][e] - mx);
          sum += ev;
          o[e] = f2bf(ev);
        }
        *(u16x8*)(row + j * 8) = o;
      }
      {
        const float ev = __expf((float)c[6][0] - mx);
        sum += ev;
        u16x8 o = {};
        o[0] = f2bf(ev);
        *(u16x8*)(row + 48) = o;
      }
      linv[tid] = __builtin_amdgcn_rcpf(sum);
    } else {
      linv[tid] = 1.0f;
    }
  }
  __syncthreads();

  // ---- PV: O[n][d] = inv[n] * sum_m E[n][m] V[m][d]; V^T zero-padded m in [49,64) ----
  for (int i = 0; i < 4; ++i) {
    const int pair = wv * 4 + i;
    const int br = pair >> 3, h = pair & 7;
    const ushort_t* vt = (br ? vtB : vtA) + (size_t)(win * 8 + h) * VTP;
    const ushort_t* Sp = S + pair * 896;
    floatx4 acc[2] = {};
#pragma unroll
    for (int ks = 0; ks < 2; ++ks) {
      const bf16x8 af = *(const bf16x8*)(Sp + l16 * 56 + ks * 32 + quad * 8);
#pragma unroll
      for (int nt = 0; nt < 2; ++nt) {
        const bf16x8 bv = *(const bf16x8*)(vt + (nt * 16 + l16) * 64 + ks * 32 + quad * 8);
        acc[nt] = __builtin_amdgcn_mfma_f32_16x16x32_bf16(af, bv, acc[nt], 0, 0, 0);
      }
    }
    ushort_t* Ob = Obase + (size_t)br * TCsz + (size_t)(win * 49 + r0) * 256 + h * 32;
#pragma unroll
    for (int nt = 0; nt < 2; ++nt)
#pragma unroll
      for (int r = 0; r < 4; ++r) {
        const int n = quad * 4 + r;
        if (n < rows)
          Ob[(size_t)n * 256 + nt * 16 + l16] = f2bf(acc[nt][r] * linv[pair * 16 + n]);
      }
  }
}

extern "C" void kernel_launch(void* const* d_in, const int* in_sizes, int n_in,
                              void* d_out, int out_size, void* d_ws, size_t ws_size,
                              hipStream_t stream) {
  if (n_in < 29) { fprintf(stderr, "kernel_launch: expected 29 inputs, got %d\n", n_in); return; }
  const float* x      = (const float*)d_in[0];
  const float* xsar   = (const float*)d_in[1];
  const float* ln1_g  = (const float*)d_in[2];
  const float* ln1_b  = (const float*)d_in[3];
  const float* ln1s_g = (const float*)d_in[4];
  const float* ln1s_b = (const float*)d_in[5];
  const float* qkv_w  = (const float*)d_in[6];
  const float* qkv_b  = (const float*)d_in[7];
  const float* qkvs_w = (const float*)d_in[8];
  const float* qkvs_b = (const float*)d_in[9];
  const float* rpb    = (const float*)d_in[10];
  const float* fuse_w = (const float*)d_in[11];
  const float* fuse_b = (const float*)d_in[12];
  const float* proj_w = (const float*)d_in[13];
  const float* proj_b = (const float*)d_in[14];
  const float* projs_w = (const float*)d_in[15];
  const float* projs_b = (const float*)d_in[16];
  const float* ln2_g  = (const float*)d_in[17];
  const float* ln2_b  = (const float*)d_in[18];
  const float* ln2s_g = (const float*)d_in[19];
  const float* ln2s_b = (const float*)d_in[20];
  const float* fc1_w  = (const float*)d_in[21];
  const float* fc1_b  = (const float*)d_in[22];
  const float* fc2_w  = (const float*)d_in[23];
  const float* fc2_b  = (const float*)d_in[24];
  const float* fc1s_w = (const float*)d_in[25];
  const float* fc1s_b = (const float*)d_in[26];
  const float* fc2s_w = (const float*)d_in[27];
  const float* fc2s_b = (const float*)d_in[28];
  float* out = (float*)d_out;
  float* ws  = (float*)d_ws;

  const size_t need = 8 * TCsz * sizeof(float);
  if (ws_size < need) {
    fprintf(stderr, "kernel_launch: ws_size %zu < needed %zu\n", ws_size, need);
    return;
  }

  // --- workspace map (halves H) ---
  // xw[0,1TC) xws[1,2TC) | q[2,3) k[3,4) qs[5,6) ks[6,7) | VT_A/VT_B at [8TC,..)
  // O->xw slot, Os->xws, y->q, ys->k, hbuf->[4,8TC) | xr fp32 [6,7)f xrs [7,8)f
  // weights + fragment bias table just below 12TC (above vt end)
  ushort_t* H   = (ushort_t*)ws;
  ushort_t* xw  = H;
  ushort_t* xws = H + TCsz;
  ushort_t* q   = H + 2 * TCsz;   // q; k at +TCsz
  ushort_t* qs  = H + 5 * TCsz;   // qs; ks at +TCsz
  ushort_t* vtA = H + 8 * TCsz;
  ushort_t* vtB = vtA + VTSZ;
  float* xr  = ws + 6 * TCsz;
  float* xrs = ws + 7 * TCsz;
  ushort_t* y   = H + 2 * TCsz;
  ushort_t* ysb = H + 3 * TCsz;
  ushort_t* hbuf = H + 4 * TCsz;  // 4 TC halves: full M x 1024
  ushort_t* wb  = H + 12 * TCsz - 1572864;            // bf16 weights
  float* biasf = (float*)(H + 12 * TCsz - 1572864 - 262144);  // 128*64*16 fp32 = 512 KB
  ushort_t* wqkv  = wb;
  ushort_t* wqkvs = wb + 196608;
  ushort_t* wproj = wb + 393216;
  ushort_t* wprojs= wb + 458752;
  ushort_t* wfc1  = wb + 524288;
  ushort_t* wfc1s = wb + 786432;
  ushort_t* wfc2  = wb + 1048576;
  ushort_t* wfc2s = wb + 1310720;

  // 0. convert weights + fragment bias table + V^T tail zero
  f2b_k<<<768, 256, 0, stream>>>(qkv_w,  wqkv,  196608);
  f2b_k<<<768, 256, 0, stream>>>(qkvs_w, wqkvs, 196608);
  f2b_k<<<256, 256, 0, stream>>>(proj_w, wproj, 65536);
  f2b_k<<<256, 256, 0, stream>>>(projs_w,wprojs,65536);
  f2b_k<<<1024,256, 0, stream>>>(fc1_w,  wfc1,  262144);
  f2b_k<<<1024,256, 0, stream>>>(fc1s_w, wfc1s, 262144);
  f2b_k<<<1024,256, 0, stream>>>(fc2_w,  wfc2,  262144);
  f2b_k<<<1024,256, 0, stream>>>(fc2s_w, wfc2s, 262144);
  bias2_k<<<128, 64, 0, stream>>>(rpb, biasf);
  vtz_k<<<2048, 256, 0, stream>>>(vtA, vtB);

  // 1. LN1 + shift + window partition (bf16 out)
  ln_k<1><<<12544, 256, 0, stream>>>(x,    ln1_g,  ln1_b,  xw);
  ln_k<1><<<12544, 256, 0, stream>>>(xsar, ln1s_g, ln1s_b, xws);
  // 2. QKV MFMA GEMM (q pre-scaled); q,k -> [pair][n][d], V -> [pair][d][64]
  bgemm_k<0><<<dim3(6, 392), 256, 0, stream>>>(xw,  wqkv,  qkv_b,  (float*)vtA, q,  nullptr, 256, 768);
  bgemm_k<0><<<dim3(6, 392), 256, 0, stream>>>(xws, wqkvs, qkvs_b, (float*)vtB, qs, nullptr, 256, 768);
  // 3. fused attention (scores + gate + softmax + PV), both branches
  attn_k<<<4096, 256, 0, stream>>>(q, qs, vtA, vtB, biasf, fuse_w, fuse_b, H);
  // 4. proj MFMA + window-reverse + roll(+3) + residual -> fp32 xr
  bgemm_k<1><<<dim3(2, 392), 256, 0, stream>>>(H,        wproj,  proj_b,  xr,  nullptr, x,    256, 256);
  bgemm_k<1><<<dim3(2, 392), 256, 0, stream>>>(H + TCsz, wprojs, projs_b, xrs, nullptr, xsar, 256, 256);
  // 5. LN2 (bf16 out)
  ln_k<0><<<12544, 256, 0, stream>>>(xr,  ln2_g,  ln2_b,  y);
  ln_k<0><<<12544, 256, 0, stream>>>(xrs, ln2s_g, ln2s_b, ysb);
  // 6. MLP (MFMA)
  bgemm_k<2><<<dim3(8, 392), 256, 0, stream>>>(y,    wfc1,  fc1_b,  nullptr, hbuf, nullptr, 256, 1024);
  bgemm_k<3><<<dim3(2, 392), 256, 0, stream>>>(hbuf, wfc2,  fc2_b,  out,     nullptr, xr,  1024, 256);
  bgemm_k<2><<<dim3(8, 392), 256, 0, stream>>>(ysb,  wfc1s, fc1s_b, nullptr, hbuf, nullptr, 256, 1024);
  bgemm_k<3><<<dim3(2, 392), 256, 0, stream>>>(hbuf, wfc2s, fc2s_b, out + TCsz, nullptr, xrs, 1024, 256);
}

// Round 6
// 928.844 us; speedup vs baseline: 1.0447x; 1.0098x over previous
//
#include <hip/hip_runtime.h>
#include <hip/hip_bf16.h>
#include <cstdio>

typedef unsigned short ushort_t;
using bf16x8  = __attribute__((ext_vector_type(8))) __bf16;
using u16x8   = __attribute__((ext_vector_type(8))) unsigned short;
using floatx4 = __attribute__((ext_vector_type(4))) float;

// Problem constants
constexpr int    kTokens = 50176;                       // B*nW*N = 16*64*49
constexpr size_t TCsz    = (size_t)kTokens * 256;       // 12,845,056 elements
constexpr float  kScale  = 0.17677669529663687f;        // 32^-0.5
constexpr int    PSTR    = 904;                         // S pair stride (halves); 904*2B -> 8 heads on distinct banks
constexpr size_t VTP     = 2048;                        // V^T per pair: 32 d x 64 n
constexpr size_t VTSZ    = (size_t)8192 * VTP;          // halves per branch

__device__ __forceinline__ float bf2f(ushort_t u) {
  unsigned int x = (unsigned int)u << 16;
  return __uint_as_float(x);
}
__device__ __forceinline__ ushort_t f2bf(float f) {
  __hip_bfloat16 h = __float2bfloat16(f);
  return *(ushort_t*)&h;
}

// async global->LDS 16B per lane: LDS dest = wave-uniform base + lane*16
__device__ __forceinline__ void gl_lds16(const ushort_t* g, ushort_t* l) {
  __builtin_amdgcn_global_load_lds(
      (const __attribute__((address_space(1))) unsigned int*)g,
      (__attribute__((address_space(3))) unsigned int*)l, 16, 0, 0);
}

// ---------------- weight fp32 -> bf16 conversion ----------------
__global__ __launch_bounds__(256) void f2b_k(const float* __restrict__ src,
                                             ushort_t* __restrict__ dst, int n) {
  int i = blockIdx.x * 256 + threadIdx.x;
  if (i < n) dst[i] = f2bf(src[i]);
}

// ---------------- precompute rpb + shift-mask bias in MFMA C/D FRAGMENT layout ------
__global__ __launch_bounds__(64) void bias2_k(const float* __restrict__ rpb,
                                              float* __restrict__ biasf) {
  const int b = blockIdx.x;                 // ((cls*4+chunk)*8+head)
  const int head = b & 7, chunk = (b >> 3) & 3, cls = b >> 5;
  const int wh7 = cls >> 1, ww7 = cls & 1;
  const int lane = threadIdx.x;
  float* bp = biasf + ((size_t)b * 64 + lane) * 16;
#pragma unroll
  for (int nt = 0; nt < 4; ++nt) {
#pragma unroll
    for (int r = 0; r < 4; ++r) {
      const int row = chunk * 16 + (lane >> 4) * 4 + r;
      const int col = nt * 16 + (lane & 15);
      float val = 0.0f;
      if (row < 49 && col < 49) {
        const int yi = row / 7, xi = row % 7, yj = col / 7, xj = col % 7;
        val = rpb[((yi - yj + 6) * 13 + (xi - xj + 6)) * 8 + head];
        const int li = (wh7 ? (yi < 4 ? 1 : 2) : 0) * 3 + (ww7 ? (xi < 4 ? 1 : 2) : 0);
        const int lj = (wh7 ? (yj < 4 ? 1 : 2) : 0) * 3 + (ww7 ? (xj < 4 ? 1 : 2) : 0);
        if (li != lj) val -= 100.0f;
      }
      bp[nt * 4 + r] = val;
    }
  }
}

// ---------------- zero V^T n-tail [48,64) (NaN guard for PV K-tail) ----------------
__global__ __launch_bounds__(256) void vtz_k(ushort_t* __restrict__ vtA,
                                             ushort_t* __restrict__ vtB) {
  const int id = blockIdx.x * 256 + threadIdx.x;       // 524288 threads
  ushort_t* base = (id < 262144) ? vtA : vtB;
  const size_t r = (size_t)(id & 262143) * 64;
  const uint4 z{0, 0, 0, 0};
  *(uint4*)(base + r + 48) = z;
  *(uint4*)(base + r + 56) = z;
}

// ---------------- LN (wave per token) + optional roll/window scatter -> bf16 ----------------
template <int SHIFTED>
__global__ __launch_bounds__(256) void ln_k(const float* __restrict__ x,
                                            const float* __restrict__ g,
                                            const float* __restrict__ b,
                                            ushort_t* __restrict__ yout) {
  const int wave = threadIdx.x >> 6, lane = threadIdx.x & 63;
  const int t = blockIdx.x * 4 + wave;
  size_t src;
  if (SHIFTED) {
    int bb = t / 3136, r = t % 3136;
    int wi = r / 49, n = r % 49;
    int hp = (wi >> 3) * 7 + n / 7;
    int wp = (wi & 7) * 7 + n % 7;
    int sh = hp + 3; if (sh >= 56) sh -= 56;
    int sw = wp + 3; if (sw >= 56) sw -= 56;
    src = ((size_t)bb * 3136 + sh * 56 + sw) * 256;
  } else {
    src = (size_t)t * 256;
  }
  const float4 v4 = *(const float4*)(x + src + lane * 4);
  float s  = v4.x + v4.y + v4.z + v4.w;
  float s2 = v4.x * v4.x + v4.y * v4.y + v4.z * v4.z + v4.w * v4.w;
#pragma unroll
  for (int off = 32; off > 0; off >>= 1) {
    s  += __shfl_xor(s,  off);
    s2 += __shfl_xor(s2, off);
  }
  const float mean = s * (1.0f / 256.0f);
  const float var  = s2 * (1.0f / 256.0f) - mean * mean;
  const float rstd = rsqrtf(var + 1e-5f);
  const float4 g4 = *(const float4*)(g + lane * 4);
  const float4 b4 = *(const float4*)(b + lane * 4);
  ushort4 o;
  o.x = f2bf((v4.x - mean) * rstd * g4.x + b4.x);
  o.y = f2bf((v4.y - mean) * rstd * g4.y + b4.y);
  o.z = f2bf((v4.z - mean) * rstd * g4.z + b4.z);
  o.w = f2bf((v4.w - mean) * rstd * g4.w + b4.w);
  *(ushort4*)(yout + (size_t)t * 256 + lane * 4) = o;
}

// ---------------- bf16 MFMA GEMM: out = A(M x K,bf16) @ W(N x K,bf16)^T ----------------
// 128x128 tile, BK=32, 4 waves. DOUBLE-BUFFERED global_load_lds staging:
// issue stage(t+1) -> compute tile t -> ONE __syncthreads per iter (HBM latency
// hidden under the 16 MFMAs). XOR-swizzled source/read. XCD chunk swizzle.
template <int MODE>
__global__ __launch_bounds__(256) void bgemm_k(const ushort_t* __restrict__ A,
                                               const ushort_t* __restrict__ W,
                                               const float* __restrict__ bias,
                                               float* __restrict__ outf,
                                               ushort_t* __restrict__ outb,
                                               const float* __restrict__ aux,
                                               int K, int Nc) {
  __shared__ __align__(16) ushort_t As[2 * 4096];
  __shared__ __align__(16) ushort_t Bs[2 * 4096];
  const int tid = threadIdx.x;
  const int nbx = gridDim.x;
  const int nwg = nbx * gridDim.y;
  int flat = blockIdx.y * nbx + blockIdx.x;
  {
    const int xcd = flat & 7, idx = flat >> 3;
    const int q8 = nwg >> 3, r8 = nwg & 7;
    flat = (xcd < r8 ? xcd * (q8 + 1) : r8 * (q8 + 1) + (xcd - r8) * q8) + idx;
  }
  const int m0 = (flat / nbx) * 128;
  const int n0 = (flat % nbx) * 128;
  const int lane = tid & 63, wv = tid >> 6;
  const int wm = (wv >> 1) * 64, wn = (wv & 1) * 64;
  const int l16 = lane & 15, quad = lane >> 4;

  const int srow = tid >> 2;
  const int gkc  = (tid & 3) ^ ((tid >> 3) & 3);
  const ushort_t* Ag0 = A + (size_t)(m0 + srow) * K + gkc * 8;
  const ushort_t* Ag1 = A + (size_t)(m0 + 64 + srow) * K + gkc * 8;
  const ushort_t* Wg0 = W + (size_t)(n0 + srow) * K + gkc * 8;
  const ushort_t* Wg1 = W + (size_t)(n0 + 64 + srow) * K + gkc * 8;
  const int ldsW0 = wv * 512, ldsW1 = 2048 + wv * 512;

  const int kcq = quad ^ ((l16 >> 1) & 3);
  const int arA = (wm + l16) * 32 + kcq * 8;
  const int arB = (wn + l16) * 32 + kcq * 8;

  const int NT = K >> 5;
  floatx4 acc[4][4] = {};

  // prologue: stage tile 0 into buffer 0
  gl_lds16(Ag0, As + ldsW0);
  gl_lds16(Ag1, As + ldsW1);
  gl_lds16(Wg0, Bs + ldsW0);
  gl_lds16(Wg1, Bs + ldsW1);
  __syncthreads();

  int cur = 0;
  for (int t = 0; t < NT; ++t) {
    if (t + 1 < NT) {                    // stage next tile into the other buffer
      const int k0 = (t + 1) * 32;
      const int nb = (cur ^ 1) * 4096;
      gl_lds16(Ag0 + k0, As + nb + ldsW0);
      gl_lds16(Ag1 + k0, As + nb + ldsW1);
      gl_lds16(Wg0 + k0, Bs + nb + ldsW0);
      gl_lds16(Wg1 + k0, Bs + nb + ldsW1);
    }
    const int cb = cur * 4096;
    bf16x8 af[4], bfr[4];
#pragma unroll
    for (int tt = 0; tt < 4; ++tt) {
      af[tt]  = *(const bf16x8*)&As[cb + arA + tt * 512];
      bfr[tt] = *(const bf16x8*)&Bs[cb + arB + tt * 512];
    }
#pragma unroll
    for (int mt = 0; mt < 4; ++mt)
#pragma unroll
      for (int nt = 0; nt < 4; ++nt)
        acc[mt][nt] = __builtin_amdgcn_mfma_f32_16x16x32_bf16(af[mt], bfr[nt], acc[mt][nt], 0, 0, 0);
    __syncthreads();                     // drains vmcnt (stage) + lgkm (reads)
    cur ^= 1;
  }

  // C/D layout: col = lane&15, row = quad*4 + reg.
  if (MODE == 0) {
    int wis[16], ns[16];
#pragma unroll
    for (int mt = 0; mt < 4; ++mt) {
      int row = m0 + wm + mt * 16 + quad * 4;
      int wi = row / 49, n = row - wi * 49;
#pragma unroll
      for (int r = 0; r < 4; ++r) {
        wis[mt * 4 + r] = wi; ns[mt * 4 + r] = n;
        if (++n == 49) { n = 0; ++wi; }
      }
    }
    if (n0 < 512) {          // q,k: [pair][n][32]
      size_t rb[16];
#pragma unroll
      for (int i = 0; i < 16; ++i) rb[i] = (size_t)wis[i] * 12544 + (size_t)ns[i] * 32;
#pragma unroll
      for (int nt = 0; nt < 4; ++nt) {
        const int col = n0 + wn + nt * 16 + l16;
        const int which = col >> 8, head = (col >> 5) & 7, d = col & 31;
        const float bv = bias[col];
        const float sc = (which == 0) ? kScale : 1.0f;
        ushort_t* ob = outb + (size_t)which * TCsz + head * 1568 + d;
#pragma unroll
        for (int i = 0; i < 16; ++i)
          ob[rb[i]] = f2bf((acc[i >> 2][nt][i & 3] + bv) * sc);
      }
    } else {                 // v: transposed [pair][d][64]
      size_t rb[16];
#pragma unroll
      for (int i = 0; i < 16; ++i) rb[i] = (size_t)wis[i] * 16384 + (size_t)ns[i];
      ushort_t* vtb = (ushort_t*)outf;
#pragma unroll
      for (int nt = 0; nt < 4; ++nt) {
        const int col = n0 + wn + nt * 16 + l16;
        const int head = (col >> 5) & 7, d = col & 31;
        const float bv = bias[col];
        ushort_t* ob = vtb + head * 2048 + d * 64;
#pragma unroll
        for (int i = 0; i < 16; ++i)
          ob[rb[i]] = f2bf(acc[i >> 2][nt][i & 3] + bv);
      }
    }
  } else if (MODE == 1) {
    size_t rb[16];
#pragma unroll
    for (int mt = 0; mt < 4; ++mt) {
#pragma unroll
      for (int r = 0; r < 4; ++r) {
        const int row = m0 + wm + mt * 16 + quad * 4 + r;
        const int wi = row / 49, n = row - wi * 49;
        const int b = wi >> 6, wl = wi & 63;
        int h = (wl >> 3) * 7 + n / 7 + 3; if (h >= 56) h -= 56;
        int w = (wl & 7) * 7 + n % 7 + 3; if (w >= 56) w -= 56;
        rb[mt * 4 + r] = ((size_t)(b * 3136 + h * 56 + w)) * 256;
      }
    }
#pragma unroll
    for (int nt = 0; nt < 4; ++nt) {
      const int col = n0 + wn + nt * 16 + l16;
      const float bv = bias[col];
#pragma unroll
      for (int i = 0; i < 16; ++i) {
        const size_t idx = rb[i] + col;
        outf[idx] = aux[idx] + acc[i >> 2][nt][i & 3] + bv;
      }
    }
  } else if (MODE == 2) {
    size_t rb[16];
#pragma unroll
    for (int mt = 0; mt < 4; ++mt)
#pragma unroll
      for (int r = 0; r < 4; ++r)
        rb[mt * 4 + r] = (size_t)(m0 + wm + mt * 16 + quad * 4 + r) * Nc;
#pragma unroll
    for (int nt = 0; nt < 4; ++nt) {
      const int col = n0 + wn + nt * 16 + l16;
      const float bv = bias[col];
#pragma unroll
      for (int i = 0; i < 16; ++i) {
        float val = acc[i >> 2][nt][i & 3] + bv;
        val = 0.5f * val * (1.0f + erff(val * 0.70710678118654752f));
        outb[rb[i] + col] = f2bf(val);
      }
    }
  } else {
    size_t rb[16];
#pragma unroll
    for (int mt = 0; mt < 4; ++mt)
#pragma unroll
      for (int r = 0; r < 4; ++r)
        rb[mt * 4 + r] = (size_t)(m0 + wm + mt * 16 + quad * 4 + r) * 256;
#pragma unroll
    for (int nt = 0; nt < 4; ++nt) {
      const int col = n0 + wn + nt * 16 + l16;
      const float bv = bias[col];
#pragma unroll
      for (int i = 0; i < 16; ++i) {
        const size_t idx = rb[i] + col;
        outf[idx] = aux[idx] + acc[i >> 2][nt][i & 3] + bv;
      }
    }
  }
}

// ---------------- fused attention: scores(MFMA) + bias + gate + softmax + PV(MFMA) ----
// block = (window, 16-row chunk); 4096 blocks, 256 threads (4 waves, 4 pairs/wave).
// S in LDS bf16, pair stride 904 (gate's 8-head strides land on distinct banks).
// Softmax leaves UNNORMALIZED exp in S; 1/sum applied in the PV epilogue.
__global__ __launch_bounds__(256) void attn_k(const ushort_t* __restrict__ qA,
                                              const ushort_t* __restrict__ qB,
                                              const ushort_t* __restrict__ vtA,
                                              const ushort_t* __restrict__ vtB,
                                              const float* __restrict__ biasf,
                                              const float* __restrict__ fw,
                                              const float* __restrict__ fb,
                                              ushort_t* __restrict__ Obase) {
  __shared__ __align__(16) ushort_t S[16 * PSTR];
  __shared__ float fwl[64], fbl[8];
  __shared__ float linv[256];
  const int tid = threadIdx.x, lane = tid & 63, wv = tid >> 6;
  const int l16 = lane & 15, quad = lane >> 4;
  int bx = blockIdx.x;
  bx = (bx & 7) * 512 + (bx >> 3);        // XCD chunk swizzle (4096 = 8*512)
  const int win = bx >> 2, chunk = bx & 3;
  const int r0 = chunk * 16;
  const int rows = (r0 + 16 <= 49) ? 16 : (49 - r0);

  // zero tail rows (chunk 3) + per-pair pads [896,904) (PV K-tail reads them)
  if (rows < 16) {
    const int per = (16 - rows) * 7;               // uint4 per pair
    for (int u = tid; u < 16 * per; u += 256) {
      const int pr = u / per, off = u - pr * per;
      *(uint4*)(S + pr * PSTR + rows * 56 + off * 8) = uint4{0, 0, 0, 0};
    }
  }
  if (tid < 16) *(uint4*)(S + tid * PSTR + 896) = uint4{0, 0, 0, 0};
  if (tid < 64) fwl[tid] = fw[tid];
  if (tid < 8)  fbl[tid] = fb[tid];
  __syncthreads();

  const int wl = win & 63;
  const int cls = (((wl >> 3) == 7) ? 2 : 0) + (((wl & 7) == 7) ? 1 : 0);

  // ---- scores: 4 pairs per wave, K=32 single MFMA step; fragment-layout bias ----
  const int qrow = (r0 + l16 <= 48) ? (r0 + l16) : 48;
#pragma unroll
  for (int i = 0; i < 4; ++i) {
    const int pair = wv * 4 + i;
    const int br = pair >> 3, h = pair & 7;
    const ushort_t* qb = (br ? qB : qA) + (size_t)(win * 8 + h) * 1568;
    const ushort_t* kb = qb + TCsz;
    const bf16x8 af = *(const bf16x8*)(qb + qrow * 32 + quad * 8);
    floatx4 acc[4];
#pragma unroll
    for (int nt = 0; nt < 4; ++nt) {
      const int krow = nt * 16 + l16;
      const int krc = (krow <= 48) ? krow : 48;
      const bf16x8 bfr = *(const bf16x8*)(kb + krc * 32 + quad * 8);
      acc[nt] = __builtin_amdgcn_mfma_f32_16x16x32_bf16(af, bfr, (floatx4){0.f, 0.f, 0.f, 0.f}, 0, 0, 0);
    }
    const float* bfp = biasf + ((size_t)((cls * 4 + chunk) * 8 + h) * 64 + lane) * 16;
    ushort_t* Sp = S + pair * PSTR;
#pragma unroll
    for (int nt = 0; nt < 4; ++nt) {
      const int col = nt * 16 + l16;
      if (col >= 56) continue;
      const float4 bv4 = *(const float4*)(bfp + nt * 4);
      const float bvv[4] = {bv4.x, bv4.y, bv4.z, bv4.w};
#pragma unroll
      for (int r = 0; r < 4; ++r) {
        const int lrow = quad * 4 + r;
        if (lrow < rows)
          Sp[lrow * 56 + col] = (col < 49) ? f2bf(acc[nt][r] + bvv[r]) : (ushort_t)0;
      }
    }
  }
  __syncthreads();

  // ---- gate: s_A <- s_A + d * sigmoid(fw @ d + fb) ----
  const int np = rows * 49;
  for (int p = tid; p < np; p += 256) {
    const int lr = p / 49, c = p - lr * 49;
    const int off = lr * 56 + c;
    float sA[8], dd[8];
#pragma unroll
    for (int h = 0; h < 8; ++h) {
      sA[h] = bf2f(S[h * PSTR + off]);
      dd[h] = bf2f(S[(8 + h) * PSTR + off]) - sA[h];
    }
#pragma unroll
    for (int o = 0; o < 8; ++o) {
      float g = fbl[o];
#pragma unroll
      for (int h = 0; h < 8; ++h) g = fmaf(fwl[o * 8 + h], dd[h], g);
      g = __builtin_amdgcn_rcpf(1.0f + __expf(-g));
      S[o * PSTR + off] = f2bf(sA[o] + dd[o] * g);
    }
  }
  __syncthreads();

  // ---- softmax (vectorized, unnormalized): one thread per (pair, row) ----
  {
    const int lr = tid & 15, ph = tid >> 4;
    if (lr < rows) {
      ushort_t* row = S + ph * PSTR + lr * 56;
      bf16x8 c[7];
#pragma unroll
      for (int j = 0; j < 7; ++j) c[j] = *(const bf16x8*)(row + j * 8);
      float mx = -1e30f;
#pragma unroll
      for (int j = 0; j < 6; ++j)
#pragma unroll
        for (int e = 0; e < 8; ++e) mx = fmaxf(mx, (float)c[j][e]);
      mx = fmaxf(mx, (float)c[6][0]);
      float sum = 0.0f;
#pragma unroll
      for (int j = 0; j < 6; ++j) {
        u16x8 o;
#pragma unroll
        for (int e = 0; e < 8; ++e) {
          const float ev = __expf((float)c[j][e] - mx);
          sum += ev;
          o[e] = f2bf(ev);
        }
        *(u16x8*)(row + j * 8) = o;
      }
      {
        const float ev = __expf((float)c[6][0] - mx);
        sum += ev;
        u16x8 o = {};
        o[0] = f2bf(ev);
        *(u16x8*)(row + 48) = o;
      }
      linv[tid] = __builtin_amdgcn_rcpf(sum);
    } else {
      linv[tid] = 1.0f;
    }
  }
  __syncthreads();

  // ---- PV: O[n][d] = inv[n] * sum_m E[n][m] V[m][d]; V^T zero-padded m in [49,64) ----
#pragma unroll
  for (int i = 0; i < 4; ++i) {
    const int pair = wv * 4 + i;
    const int br = pair >> 3, h = pair & 7;
    const ushort_t* vt = (br ? vtB : vtA) + (size_t)(win * 8 + h) * VTP;
    const ushort_t* Sp = S + pair * PSTR;
    floatx4 acc[2] = {};
#pragma unroll
    for (int ks = 0; ks < 2; ++ks) {
      const bf16x8 af = *(const bf16x8*)(Sp + l16 * 56 + ks * 32 + quad * 8);
#pragma unroll
      for (int nt = 0; nt < 2; ++nt) {
        const bf16x8 bv = *(const bf16x8*)(vt + (nt * 16 + l16) * 64 + ks * 32 + quad * 8);
        acc[nt] = __builtin_amdgcn_mfma_f32_16x16x32_bf16(af, bv, acc[nt], 0, 0, 0);
      }
    }
    ushort_t* Ob = Obase + (size_t)br * TCsz + (size_t)(win * 49 + r0) * 256 + h * 32;
#pragma unroll
    for (int nt = 0; nt < 2; ++nt)
#pragma unroll
      for (int r = 0; r < 4; ++r) {
        const int n = quad * 4 + r;
        if (n < rows)
          Ob[(size_t)n * 256 + nt * 16 + l16] = f2bf(acc[nt][r] * linv[pair * 16 + n]);
      }
  }
}

extern "C" void kernel_launch(void* const* d_in, const int* in_sizes, int n_in,
                              void* d_out, int out_size, void* d_ws, size_t ws_size,
                              hipStream_t stream) {
  if (n_in < 29) { fprintf(stderr, "kernel_launch: expected 29 inputs, got %d\n", n_in); return; }
  const float* x      = (const float*)d_in[0];
  const float* xsar   = (const float*)d_in[1];
  const float* ln1_g  = (const float*)d_in[2];
  const float* ln1_b  = (const float*)d_in[3];
  const float* ln1s_g = (const float*)d_in[4];
  const float* ln1s_b = (const float*)d_in[5];
  const float* qkv_w  = (const float*)d_in[6];
  const float* qkv_b  = (const float*)d_in[7];
  const float* qkvs_w = (const float*)d_in[8];
  const float* qkvs_b = (const float*)d_in[9];
  const float* rpb    = (const float*)d_in[10];
  const float* fuse_w = (const float*)d_in[11];
  const float* fuse_b = (const float*)d_in[12];
  const float* proj_w = (const float*)d_in[13];
  const float* proj_b = (const float*)d_in[14];
  const float* projs_w = (const float*)d_in[15];
  const float* projs_b = (const float*)d_in[16];
  const float* ln2_g  = (const float*)d_in[17];
  const float* ln2_b  = (const float*)d_in[18];
  const float* ln2s_g = (const float*)d_in[19];
  const float* ln2s_b = (const float*)d_in[20];
  const float* fc1_w  = (const float*)d_in[21];
  const float* fc1_b  = (const float*)d_in[22];
  const float* fc2_w  = (const float*)d_in[23];
  const float* fc2_b  = (const float*)d_in[24];
  const float* fc1s_w = (const float*)d_in[25];
  const float* fc1s_b = (const float*)d_in[26];
  const float* fc2s_w = (const float*)d_in[27];
  const float* fc2s_b = (const float*)d_in[28];
  float* out = (float*)d_out;
  float* ws  = (float*)d_ws;

  const size_t need = 8 * TCsz * sizeof(float);
  if (ws_size < need) {
    fprintf(stderr, "kernel_launch: ws_size %zu < needed %zu\n", ws_size, need);
    return;
  }

  // --- workspace map (halves H) ---
  ushort_t* H   = (ushort_t*)ws;
  ushort_t* xw  = H;
  ushort_t* xws = H + TCsz;
  ushort_t* q   = H + 2 * TCsz;   // q; k at +TCsz
  ushort_t* qs  = H + 5 * TCsz;   // qs; ks at +TCsz
  ushort_t* vtA = H + 8 * TCsz;
  ushort_t* vtB = vtA + VTSZ;
  float* xr  = ws + 6 * TCsz;
  float* xrs = ws + 7 * TCsz;
  ushort_t* y   = H + 2 * TCsz;
  ushort_t* ysb = H + 3 * TCsz;
  ushort_t* hbuf = H + 4 * TCsz;  // 4 TC halves: full M x 1024
  ushort_t* wb  = H + 12 * TCsz - 1572864;            // bf16 weights
  float* biasf = (float*)(H + 12 * TCsz - 1572864 - 262144);  // 128*64*16 fp32 = 512 KB
  ushort_t* wqkv  = wb;
  ushort_t* wqkvs = wb + 196608;
  ushort_t* wproj = wb + 393216;
  ushort_t* wprojs= wb + 458752;
  ushort_t* wfc1  = wb + 524288;
  ushort_t* wfc1s = wb + 786432;
  ushort_t* wfc2  = wb + 1048576;
  ushort_t* wfc2s = wb + 1310720;

  // 0. convert weights + fragment bias table + V^T tail zero
  f2b_k<<<768, 256, 0, stream>>>(qkv_w,  wqkv,  196608);
  f2b_k<<<768, 256, 0, stream>>>(qkvs_w, wqkvs, 196608);
  f2b_k<<<256, 256, 0, stream>>>(proj_w, wproj, 65536);
  f2b_k<<<256, 256, 0, stream>>>(projs_w,wprojs,65536);
  f2b_k<<<1024,256, 0, stream>>>(fc1_w,  wfc1,  262144);
  f2b_k<<<1024,256, 0, stream>>>(fc1s_w, wfc1s, 262144);
  f2b_k<<<1024,256, 0, stream>>>(fc2_w,  wfc2,  262144);
  f2b_k<<<1024,256, 0, stream>>>(fc2s_w, wfc2s, 262144);
  bias2_k<<<128, 64, 0, stream>>>(rpb, biasf);
  vtz_k<<<2048, 256, 0, stream>>>(vtA, vtB);

  // 1. LN1 + shift + window partition (bf16 out)
  ln_k<1><<<12544, 256, 0, stream>>>(x,    ln1_g,  ln1_b,  xw);
  ln_k<1><<<12544, 256, 0, stream>>>(xsar, ln1s_g, ln1s_b, xws);
  // 2. QKV MFMA GEMM (q pre-scaled); q,k -> [pair][n][d], V -> [pair][d][64]
  bgemm_k<0><<<dim3(6, 392), 256, 0, stream>>>(xw,  wqkv,  qkv_b,  (float*)vtA, q,  nullptr, 256, 768);
  bgemm_k<0><<<dim3(6, 392), 256, 0, stream>>>(xws, wqkvs, qkvs_b, (float*)vtB, qs, nullptr, 256, 768);
  // 3. fused attention (scores + gate + softmax + PV), both branches
  attn_k<<<4096, 256, 0, stream>>>(q, qs, vtA, vtB, biasf, fuse_w, fuse_b, H);
  // 4. proj MFMA + window-reverse + roll(+3) + residual -> fp32 xr
  bgemm_k<1><<<dim3(2, 392), 256, 0, stream>>>(H,        wproj,  proj_b,  xr,  nullptr, x,    256, 256);
  bgemm_k<1><<<dim3(2, 392), 256, 0, stream>>>(H + TCsz, wprojs, projs_b, xrs, nullptr, xsar, 256, 256);
  // 5. LN2 (bf16 out)
  ln_k<0><<<12544, 256, 0, stream>>>(xr,  ln2_g,  ln2_b,  y);
  ln_k<0><<<12544, 256, 0, stream>>>(xrs, ln2s_g, ln2s_b, ysb);
  // 6. MLP (MFMA)
  bgemm_k<2><<<dim3(8, 392), 256, 0, stream>>>(y,    wfc1,  fc1_b,  nullptr, hbuf, nullptr, 256, 1024);
  bgemm_k<3><<<dim3(2, 392), 256, 0, stream>>>(hbuf, wfc2,  fc2_b,  out,     nullptr, xr,  1024, 256);
  bgemm_k<2><<<dim3(8, 392), 256, 0, stream>>>(ysb,  wfc1s, fc1s_b, nullptr, hbuf, nullptr, 256, 1024);
  bgemm_k<3><<<dim3(2, 392), 256, 0, stream>>>(hbuf, wfc2s, fc2s_b, out + TCsz, nullptr, xrs, 1024, 256);
}

// Round 7
// 909.308 us; speedup vs baseline: 1.0672x; 1.0215x over previous
//
#include <hip/hip_runtime.h>
#include <hip/hip_bf16.h>
#include <cstdio>

typedef unsigned short ushort_t;
using bf16x8  = __attribute__((ext_vector_type(8))) __bf16;
using u16x8   = __attribute__((ext_vector_type(8))) unsigned short;
using floatx4 = __attribute__((ext_vector_type(4))) float;

// Problem constants
constexpr int    kTokens = 50176;                       // B*nW*N = 16*64*49
constexpr size_t TCsz    = (size_t)kTokens * 256;       // 12,845,056 elements
constexpr float  kScale  = 0.17677669529663687f;        // 32^-0.5
constexpr int    PSTR    = 904;                         // S pair stride (halves)
constexpr size_t VTP     = 2048;                        // V^T per pair: 32 d x 64 n
constexpr size_t VTSZ    = (size_t)8192 * VTP;          // halves per branch

__device__ __forceinline__ float bf2f(ushort_t u) {
  unsigned int x = (unsigned int)u << 16;
  return __uint_as_float(x);
}
__device__ __forceinline__ ushort_t f2bf(float f) {
  __hip_bfloat16 h = __float2bfloat16(f);
  return *(ushort_t*)&h;
}

// ---------------- weight fp32 -> bf16 conversion ----------------
__global__ __launch_bounds__(256) void f2b_k(const float* __restrict__ src,
                                             ushort_t* __restrict__ dst, int n) {
  int i = blockIdx.x * 256 + threadIdx.x;
  if (i < n) dst[i] = f2bf(src[i]);
}

// ---------------- precompute rpb + shift-mask bias in MFMA C/D FRAGMENT layout ------
__global__ __launch_bounds__(64) void bias2_k(const float* __restrict__ rpb,
                                              float* __restrict__ biasf) {
  const int b = blockIdx.x;                 // ((cls*4+chunk)*8+head)
  const int head = b & 7, chunk = (b >> 3) & 3, cls = b >> 5;
  const int wh7 = cls >> 1, ww7 = cls & 1;
  const int lane = threadIdx.x;
  float* bp = biasf + ((size_t)b * 64 + lane) * 16;
#pragma unroll
  for (int nt = 0; nt < 4; ++nt) {
#pragma unroll
    for (int r = 0; r < 4; ++r) {
      const int row = chunk * 16 + (lane >> 4) * 4 + r;
      const int col = nt * 16 + (lane & 15);
      float val = 0.0f;
      if (row < 49 && col < 49) {
        const int yi = row / 7, xi = row % 7, yj = col / 7, xj = col % 7;
        val = rpb[((yi - yj + 6) * 13 + (xi - xj + 6)) * 8 + head];
        const int li = (wh7 ? (yi < 4 ? 1 : 2) : 0) * 3 + (ww7 ? (xi < 4 ? 1 : 2) : 0);
        const int lj = (wh7 ? (yj < 4 ? 1 : 2) : 0) * 3 + (ww7 ? (xj < 4 ? 1 : 2) : 0);
        if (li != lj) val -= 100.0f;
      }
      bp[nt * 4 + r] = val;
    }
  }
}

// ---------------- zero V^T n-tail [48,64) (NaN guard for PV K-tail) ----------------
__global__ __launch_bounds__(256) void vtz_k(ushort_t* __restrict__ vtA,
                                             ushort_t* __restrict__ vtB) {
  const int id = blockIdx.x * 256 + threadIdx.x;       // 524288 threads
  ushort_t* base = (id < 262144) ? vtA : vtB;
  const size_t r = (size_t)(id & 262143) * 64;
  const uint4 z{0, 0, 0, 0};
  *(uint4*)(base + r + 48) = z;
  *(uint4*)(base + r + 56) = z;
}

// ---------------- LN (wave per token) + optional roll/window scatter -> bf16 ----------------
template <int SHIFTED>
__global__ __launch_bounds__(256) void ln_k(const float* __restrict__ x,
                                            const float* __restrict__ g,
                                            const float* __restrict__ b,
                                            ushort_t* __restrict__ yout) {
  const int wave = threadIdx.x >> 6, lane = threadIdx.x & 63;
  const int t = blockIdx.x * 4 + wave;
  size_t src;
  if (SHIFTED) {
    int bb = t / 3136, r = t % 3136;
    int wi = r / 49, n = r % 49;
    int hp = (wi >> 3) * 7 + n / 7;
    int wp = (wi & 7) * 7 + n % 7;
    int sh = hp + 3; if (sh >= 56) sh -= 56;
    int sw = wp + 3; if (sw >= 56) sw -= 56;
    src = ((size_t)bb * 3136 + sh * 56 + sw) * 256;
  } else {
    src = (size_t)t * 256;
  }
  const float4 v4 = *(const float4*)(x + src + lane * 4);
  float s  = v4.x + v4.y + v4.z + v4.w;
  float s2 = v4.x * v4.x + v4.y * v4.y + v4.z * v4.z + v4.w * v4.w;
#pragma unroll
  for (int off = 32; off > 0; off >>= 1) {
    s  += __shfl_xor(s,  off);
    s2 += __shfl_xor(s2, off);
  }
  const float mean = s * (1.0f / 256.0f);
  const float var  = s2 * (1.0f / 256.0f) - mean * mean;
  const float rstd = rsqrtf(var + 1e-5f);
  const float4 g4 = *(const float4*)(g + lane * 4);
  const float4 b4 = *(const float4*)(b + lane * 4);
  ushort4 o;
  o.x = f2bf((v4.x - mean) * rstd * g4.x + b4.x);
  o.y = f2bf((v4.y - mean) * rstd * g4.y + b4.y);
  o.z = f2bf((v4.z - mean) * rstd * g4.z + b4.z);
  o.w = f2bf((v4.w - mean) * rstd * g4.w + b4.w);
  *(ushort4*)(yout + (size_t)t * 256 + lane * 4) = o;
}

// ---------------- bf16 MFMA GEMM: out = A(M x K,bf16) @ W(N x K,bf16)^T ----------------
// 128x128 tile, BK=32, 4 waves. Reg-staged ping-pong pipeline with RAW barriers:
// loads issued 1 phase ahead stay in flight ACROSS barriers (only lgkmcnt drained).
// XOR-swizzled source/read (rule #21 pair). XCD chunk swizzle on block id.
template <int MODE>
__global__ __launch_bounds__(256) void bgemm_k(const ushort_t* __restrict__ A,
                                               const ushort_t* __restrict__ W,
                                               const float* __restrict__ bias,
                                               float* __restrict__ outf,
                                               ushort_t* __restrict__ outb,
                                               const float* __restrict__ aux,
                                               int K, int Nc) {
  __shared__ __align__(16) ushort_t As[2 * 4096];
  __shared__ __align__(16) ushort_t Bs[2 * 4096];
  const int tid = threadIdx.x;
  const int nbx = gridDim.x;
  const int nwg = nbx * gridDim.y;
  int flat = blockIdx.y * nbx + blockIdx.x;
  {
    const int xcd = flat & 7, idx = flat >> 3;
    const int q8 = nwg >> 3, r8 = nwg & 7;
    flat = (xcd < r8 ? xcd * (q8 + 1) : r8 * (q8 + 1) + (xcd - r8) * q8) + idx;
  }
  const int m0 = (flat / nbx) * 128;
  const int n0 = (flat % nbx) * 128;
  const int lane = tid & 63, wv = tid >> 6;
  const int wm = (wv >> 1) * 64, wn = (wv & 1) * 64;
  const int l16 = lane & 15, quad = lane >> 4;

  const int srow = tid >> 2;
  const int gkc  = (tid & 3) ^ ((tid >> 3) & 3);
  const ushort_t* Ag0 = A + (size_t)(m0 + srow) * K + gkc * 8;
  const ushort_t* Ag1 = A + (size_t)(m0 + 64 + srow) * K + gkc * 8;
  const ushort_t* Wg0 = W + (size_t)(n0 + srow) * K + gkc * 8;
  const ushort_t* Wg1 = W + (size_t)(n0 + 64 + srow) * K + gkc * 8;
  const int w0 = wv * 512 + lane * 8;           // lane's 16B slot (matches gl_lds order)
  const int w1 = 2048 + wv * 512 + lane * 8;

  const int kcq = quad ^ ((l16 >> 1) & 3);
  const int arA = (wm + l16) * 32 + kcq * 8;
  const int arB = (wn + l16) * 32 + kcq * 8;

  const int NT = K >> 5;                        // >= 8 for all call sites
  floatx4 acc[4][4] = {};
  uint4 pa0, pa1, pb0, pb1, qa0, qa1, qb0, qb1;

#define BG_LOAD(r0, r1, r2, r3, k0) { r0 = *(const uint4*)(Ag0 + (k0)); \
    r1 = *(const uint4*)(Ag1 + (k0)); r2 = *(const uint4*)(Wg0 + (k0)); \
    r3 = *(const uint4*)(Wg1 + (k0)); }
#define BG_WRITE(r0, r1, r2, r3, cb) { *(uint4*)&As[(cb) + w0] = r0; \
    *(uint4*)&As[(cb) + w1] = r1; *(uint4*)&Bs[(cb) + w0] = r2; \
    *(uint4*)&Bs[(cb) + w1] = r3; }
  // barrier that drains LDS ops only; global loads stay in flight (T3/T4)
#define BG_BAR() { __builtin_amdgcn_sched_barrier(0); \
    __builtin_amdgcn_s_waitcnt(0xC07F); /* lgkmcnt(0), vmcnt free */ \
    __builtin_amdgcn_s_barrier(); __builtin_amdgcn_sched_barrier(0); }
#define BG_COMP(cb) { bf16x8 af[4], bfr[4]; \
    _Pragma("unroll") for (int tt = 0; tt < 4; ++tt) { \
      af[tt]  = *(const bf16x8*)&As[(cb) + arA + tt * 512]; \
      bfr[tt] = *(const bf16x8*)&Bs[(cb) + arB + tt * 512]; } \
    _Pragma("unroll") for (int mt = 0; mt < 4; ++mt) \
    _Pragma("unroll") for (int nt = 0; nt < 4; ++nt) \
      acc[mt][nt] = __builtin_amdgcn_mfma_f32_16x16x32_bf16(af[mt], bfr[nt], acc[mt][nt], 0, 0, 0); }

  BG_LOAD(pa0, pa1, pb0, pb1, 0);               // tile 0
  BG_WRITE(pa0, pa1, pb0, pb1, 0);              // buf0 (waits own vmcnt)
  BG_LOAD(qa0, qa1, qb0, qb1, 32);              // tile 1 in flight across barrier
  BG_BAR();
  for (int t = 0; t < NT; t += 2) {
    if (t + 2 < NT) BG_LOAD(pa0, pa1, pb0, pb1, (t + 2) * 32);
    BG_WRITE(qa0, qa1, qb0, qb1, 4096);         // tile t+1 -> buf1
    BG_COMP(0);                                 // tile t from buf0
    BG_BAR();
    if (t + 3 < NT) BG_LOAD(qa0, qa1, qb0, qb1, (t + 3) * 32);
    if (t + 2 < NT) BG_WRITE(pa0, pa1, pb0, pb1, 0);  // tile t+2 -> buf0
    BG_COMP(4096);                              // tile t+1 from buf1
    BG_BAR();
  }
#undef BG_LOAD
#undef BG_WRITE
#undef BG_BAR
#undef BG_COMP

  // C/D layout: col = lane&15, row = quad*4 + reg.
  if (MODE == 0) {
    int wis[16], ns[16];
#pragma unroll
    for (int mt = 0; mt < 4; ++mt) {
      int row = m0 + wm + mt * 16 + quad * 4;
      int wi = row / 49, n = row - wi * 49;
#pragma unroll
      for (int r = 0; r < 4; ++r) {
        wis[mt * 4 + r] = wi; ns[mt * 4 + r] = n;
        if (++n == 49) { n = 0; ++wi; }
      }
    }
    if (n0 < 512) {          // q,k: [pair][n][32]
      size_t rb[16];
#pragma unroll
      for (int i = 0; i < 16; ++i) rb[i] = (size_t)wis[i] * 12544 + (size_t)ns[i] * 32;
#pragma unroll
      for (int nt = 0; nt < 4; ++nt) {
        const int col = n0 + wn + nt * 16 + l16;
        const int which = col >> 8, head = (col >> 5) & 7, d = col & 31;
        const float bv = bias[col];
        const float sc = (which == 0) ? kScale : 1.0f;
        ushort_t* ob = outb + (size_t)which * TCsz + head * 1568 + d;
#pragma unroll
        for (int i = 0; i < 16; ++i)
          ob[rb[i]] = f2bf((acc[i >> 2][nt][i & 3] + bv) * sc);
      }
    } else {                 // v: transposed [pair][d][64]
      size_t rb[16];
#pragma unroll
      for (int i = 0; i < 16; ++i) rb[i] = (size_t)wis[i] * 16384 + (size_t)ns[i];
      ushort_t* vtb = (ushort_t*)outf;
#pragma unroll
      for (int nt = 0; nt < 4; ++nt) {
        const int col = n0 + wn + nt * 16 + l16;
        const int head = (col >> 5) & 7, d = col & 31;
        const float bv = bias[col];
        ushort_t* ob = vtb + head * 2048 + d * 64;
#pragma unroll
        for (int i = 0; i < 16; ++i)
          ob[rb[i]] = f2bf(acc[i >> 2][nt][i & 3] + bv);
      }
    }
  } else if (MODE == 1) {
    size_t rb[16];
#pragma unroll
    for (int mt = 0; mt < 4; ++mt) {
#pragma unroll
      for (int r = 0; r < 4; ++r) {
        const int row = m0 + wm + mt * 16 + quad * 4 + r;
        const int wi = row / 49, n = row - wi * 49;
        const int b = wi >> 6, wl = wi & 63;
        int h = (wl >> 3) * 7 + n / 7 + 3; if (h >= 56) h -= 56;
        int w = (wl & 7) * 7 + n % 7 + 3; if (w >= 56) w -= 56;
        rb[mt * 4 + r] = ((size_t)(b * 3136 + h * 56 + w)) * 256;
      }
    }
#pragma unroll
    for (int nt = 0; nt < 4; ++nt) {
      const int col = n0 + wn + nt * 16 + l16;
      const float bv = bias[col];
#pragma unroll
      for (int i = 0; i < 16; ++i) {
        const size_t idx = rb[i] + col;
        outf[idx] = aux[idx] + acc[i >> 2][nt][i & 3] + bv;
      }
    }
  } else if (MODE == 2) {
    size_t rb[16];
#pragma unroll
    for (int mt = 0; mt < 4; ++mt)
#pragma unroll
      for (int r = 0; r < 4; ++r)
        rb[mt * 4 + r] = (size_t)(m0 + wm + mt * 16 + quad * 4 + r) * Nc;
#pragma unroll
    for (int nt = 0; nt < 4; ++nt) {
      const int col = n0 + wn + nt * 16 + l16;
      const float bv = bias[col];
#pragma unroll
      for (int i = 0; i < 16; ++i) {
        float val = acc[i >> 2][nt][i & 3] + bv;
        val = 0.5f * val * (1.0f + erff(val * 0.70710678118654752f));
        outb[rb[i] + col] = f2bf(val);
      }
    }
  } else {
    size_t rb[16];
#pragma unroll
    for (int mt = 0; mt < 4; ++mt)
#pragma unroll
      for (int r = 0; r < 4; ++r)
        rb[mt * 4 + r] = (size_t)(m0 + wm + mt * 16 + quad * 4 + r) * 256;
#pragma unroll
    for (int nt = 0; nt < 4; ++nt) {
      const int col = n0 + wn + nt * 16 + l16;
      const float bv = bias[col];
#pragma unroll
      for (int i = 0; i < 16; ++i) {
        const size_t idx = rb[i] + col;
        outf[idx] = aux[idx] + acc[i >> 2][nt][i & 3] + bv;
      }
    }
  }
}

// ---------------- fused attention: scores(MFMA) + bias + gate + softmax + PV(MFMA) ----
// block = (window, 16-row chunk); 4096 blocks, 256 threads (4 waves, 4 pairs/wave).
// All Q/K fragments preloaded to regs before MFMA (20 loads in flight);
// all V fragments issued right after scores barrier (fly under gate+softmax).
__global__ __launch_bounds__(256) void attn_k(const ushort_t* __restrict__ qA,
                                              const ushort_t* __restrict__ qB,
                                              const ushort_t* __restrict__ vtA,
                                              const ushort_t* __restrict__ vtB,
                                              const float* __restrict__ biasf,
                                              const float* __restrict__ fw,
                                              const float* __restrict__ fb,
                                              ushort_t* __restrict__ Obase) {
  __shared__ __align__(16) ushort_t S[16 * PSTR];
  __shared__ float fwl[64], fbl[8];
  __shared__ float linv[256];
  const int tid = threadIdx.x, lane = tid & 63, wv = tid >> 6;
  const int l16 = lane & 15, quad = lane >> 4;
  int bx = blockIdx.x;
  bx = (bx & 7) * 512 + (bx >> 3);        // XCD chunk swizzle (4096 = 8*512)
  const int win = bx >> 2, chunk = bx & 3;
  const int r0 = chunk * 16;
  const int rows = (r0 + 16 <= 49) ? 16 : (49 - r0);

  // ---- Q/K fragment preload (all 4 pairs; 20 x 16B in flight) ----
  const int qrow = (r0 + l16 <= 48) ? (r0 + l16) : 48;
  bf16x8 afq[4], bk[4][4];
#pragma unroll
  for (int i = 0; i < 4; ++i) {
    const int pair = wv * 4 + i;
    const int br = pair >> 3, h = pair & 7;
    const ushort_t* qb = (br ? qB : qA) + (size_t)(win * 8 + h) * 1568;
    const ushort_t* kb = qb + TCsz;
    afq[i] = *(const bf16x8*)(qb + qrow * 32 + quad * 8);
#pragma unroll
    for (int nt = 0; nt < 4; ++nt) {
      const int krow = nt * 16 + l16;
      const int krc = (krow <= 48) ? krow : 48;
      bk[i][nt] = *(const bf16x8*)(kb + krc * 32 + quad * 8);
    }
  }

  // zero tail rows (chunk 3) + per-pair pads [896,904) (PV K-tail reads them)
  if (rows < 16) {
    const int per = (16 - rows) * 7;               // uint4 per pair
    for (int u = tid; u < 16 * per; u += 256) {
      const int pr = u / per, off = u - pr * per;
      *(uint4*)(S + pr * PSTR + rows * 56 + off * 8) = uint4{0, 0, 0, 0};
    }
  }
  if (tid < 16) *(uint4*)(S + tid * PSTR + 896) = uint4{0, 0, 0, 0};
  if (tid < 64) fwl[tid] = fw[tid];
  if (tid < 8)  fbl[tid] = fb[tid];
  __syncthreads();

  const int wl = win & 63;
  const int cls = (((wl >> 3) == 7) ? 2 : 0) + (((wl & 7) == 7) ? 1 : 0);

  // ---- scores: MFMA + fragment-layout bias, store to LDS ----
#pragma unroll
  for (int i = 0; i < 4; ++i) {
    const int pair = wv * 4 + i;
    const int h = pair & 7;
    const float* bfp = biasf + ((size_t)((cls * 4 + chunk) * 8 + h) * 64 + lane) * 16;
    float4 bv4[4];
#pragma unroll
    for (int nt = 0; nt < 4; ++nt) bv4[nt] = *(const float4*)(bfp + nt * 4);
    floatx4 acc[4];
#pragma unroll
    for (int nt = 0; nt < 4; ++nt)
      acc[nt] = __builtin_amdgcn_mfma_f32_16x16x32_bf16(afq[i], bk[i][nt], (floatx4){0.f, 0.f, 0.f, 0.f}, 0, 0, 0);
    ushort_t* Sp = S + pair * PSTR;
#pragma unroll
    for (int nt = 0; nt < 4; ++nt) {
      const int col = nt * 16 + l16;
      if (col >= 56) continue;
      const float bvv[4] = {bv4[nt].x, bv4[nt].y, bv4[nt].z, bv4[nt].w};
#pragma unroll
      for (int r = 0; r < 4; ++r) {
        const int lrow = quad * 4 + r;
        if (lrow < rows)
          Sp[lrow * 56 + col] = (col < 49) ? f2bf(acc[nt][r] + bvv[r]) : (ushort_t)0;
      }
    }
  }
  __syncthreads();

  // ---- V fragment preload (all 4 pairs; lands during gate+softmax) ----
  bf16x8 vf[4][4];
#pragma unroll
  for (int i = 0; i < 4; ++i) {
    const int pair = wv * 4 + i;
    const int br = pair >> 3, h = pair & 7;
    const ushort_t* vt = (br ? vtB : vtA) + (size_t)(win * 8 + h) * VTP;
#pragma unroll
    for (int nt = 0; nt < 2; ++nt)
#pragma unroll
      for (int ks = 0; ks < 2; ++ks)
        vf[i][nt * 2 + ks] = *(const bf16x8*)(vt + (nt * 16 + l16) * 64 + ks * 32 + quad * 8);
  }

  // ---- gate: s_A <- s_A + d * sigmoid(fw @ d + fb) ----
  const int np = rows * 49;
  for (int p = tid; p < np; p += 256) {
    const int lr = p / 49, c = p - lr * 49;
    const int off = lr * 56 + c;
    float sA[8], dd[8];
#pragma unroll
    for (int h = 0; h < 8; ++h) {
      sA[h] = bf2f(S[h * PSTR + off]);
      dd[h] = bf2f(S[(8 + h) * PSTR + off]) - sA[h];
    }
#pragma unroll
    for (int o = 0; o < 8; ++o) {
      float g = fbl[o];
#pragma unroll
      for (int h = 0; h < 8; ++h) g = fmaf(fwl[o * 8 + h], dd[h], g);
      g = __builtin_amdgcn_rcpf(1.0f + __expf(-g));
      S[o * PSTR + off] = f2bf(sA[o] + dd[o] * g);
    }
  }
  __syncthreads();

  // ---- softmax (vectorized, unnormalized): one thread per (pair, row) ----
  {
    const int lr = tid & 15, ph = tid >> 4;
    if (lr < rows) {
      ushort_t* row = S + ph * PSTR + lr * 56;
      bf16x8 c[7];
#pragma unroll
      for (int j = 0; j < 7; ++j) c[j] = *(const bf16x8*)(row + j * 8);
      float mx = -1e30f;
#pragma unroll
      for (int j = 0; j < 6; ++j)
#pragma unroll
        for (int e = 0; e < 8; ++e) mx = fmaxf(mx, (float)c[j][e]);
      mx = fmaxf(mx, (float)c[6][0]);
      float sum = 0.0f;
#pragma unroll
      for (int j = 0; j < 6; ++j) {
        u16x8 o;
#pragma unroll
        for (int e = 0; e < 8; ++e) {
          const float ev = __expf((float)c[j][e] - mx);
          sum += ev;
          o[e] = f2bf(ev);
        }
        *(u16x8*)(row + j * 8) = o;
      }
      {
        const float ev = __expf((float)c[6][0] - mx);
        sum += ev;
        u16x8 o = {};
        o[0] = f2bf(ev);
        *(u16x8*)(row + 48) = o;
      }
      linv[tid] = __builtin_amdgcn_rcpf(sum);
    } else {
      linv[tid] = 1.0f;
    }
  }
  __syncthreads();

  // ---- PV: O[n][d] = inv[n] * sum_m E[n][m] V[m][d]; V^T zero-padded m in [49,64) ----
#pragma unroll
  for (int i = 0; i < 4; ++i) {
    const int pair = wv * 4 + i;
    const int br = pair >> 3, h = pair & 7;
    const ushort_t* Sp = S + pair * PSTR;
    floatx4 acc[2] = {};
#pragma unroll
    for (int ks = 0; ks < 2; ++ks) {
      const bf16x8 af = *(const bf16x8*)(Sp + l16 * 56 + ks * 32 + quad * 8);
#pragma unroll
      for (int nt = 0; nt < 2; ++nt)
        acc[nt] = __builtin_amdgcn_mfma_f32_16x16x32_bf16(af, vf[i][nt * 2 + ks], acc[nt], 0, 0, 0);
    }
    ushort_t* Ob = Obase + (size_t)br * TCsz + (size_t)(win * 49 + r0) * 256 + h * 32;
#pragma unroll
    for (int nt = 0; nt < 2; ++nt)
#pragma unroll
      for (int r = 0; r < 4; ++r) {
        const int n = quad * 4 + r;
        if (n < rows)
          Ob[(size_t)n * 256 + nt * 16 + l16] = f2bf(acc[nt][r] * linv[pair * 16 + n]);
      }
  }
}

extern "C" void kernel_launch(void* const* d_in, const int* in_sizes, int n_in,
                              void* d_out, int out_size, void* d_ws, size_t ws_size,
                              hipStream_t stream) {
  if (n_in < 29) { fprintf(stderr, "kernel_launch: expected 29 inputs, got %d\n", n_in); return; }
  const float* x      = (const float*)d_in[0];
  const float* xsar   = (const float*)d_in[1];
  const float* ln1_g  = (const float*)d_in[2];
  const float* ln1_b  = (const float*)d_in[3];
  const float* ln1s_g = (const float*)d_in[4];
  const float* ln1s_b = (const float*)d_in[5];
  const float* qkv_w  = (const float*)d_in[6];
  const float* qkv_b  = (const float*)d_in[7];
  const float* qkvs_w = (const float*)d_in[8];
  const float* qkvs_b = (const float*)d_in[9];
  const float* rpb    = (const float*)d_in[10];
  const float* fuse_w = (const float*)d_in[11];
  const float* fuse_b = (const float*)d_in[12];
  const float* proj_w = (const float*)d_in[13];
  const float* proj_b = (const float*)d_in[14];
  const float* projs_w = (const float*)d_in[15];
  const float* projs_b = (const float*)d_in[16];
  const float* ln2_g  = (const float*)d_in[17];
  const float* ln2_b  = (const float*)d_in[18];
  const float* ln2s_g = (const float*)d_in[19];
  const float* ln2s_b = (const float*)d_in[20];
  const float* fc1_w  = (const float*)d_in[21];
  const float* fc1_b  = (const float*)d_in[22];
  const float* fc2_w  = (const float*)d_in[23];
  const float* fc2_b  = (const float*)d_in[24];
  const float* fc1s_w = (const float*)d_in[25];
  const float* fc1s_b = (const float*)d_in[26];
  const float* fc2s_w = (const float*)d_in[27];
  const float* fc2s_b = (const float*)d_in[28];
  float* out = (float*)d_out;
  float* ws  = (float*)d_ws;

  const size_t need = 8 * TCsz * sizeof(float);
  if (ws_size < need) {
    fprintf(stderr, "kernel_launch: ws_size %zu < needed %zu\n", ws_size, need);
    return;
  }

  // --- workspace map (halves H) ---
  ushort_t* H   = (ushort_t*)ws;
  ushort_t* xw  = H;
  ushort_t* xws = H + TCsz;
  ushort_t* q   = H + 2 * TCsz;   // q; k at +TCsz
  ushort_t* qs  = H + 5 * TCsz;   // qs; ks at +TCsz
  ushort_t* vtA = H + 8 * TCsz;
  ushort_t* vtB = vtA + VTSZ;
  float* xr  = ws + 6 * TCsz;
  float* xrs = ws + 7 * TCsz;
  ushort_t* y   = H + 2 * TCsz;
  ushort_t* ysb = H + 3 * TCsz;
  ushort_t* hbuf = H + 4 * TCsz;  // 4 TC halves: full M x 1024
  ushort_t* wb  = H + 12 * TCsz - 1572864;            // bf16 weights
  float* biasf = (float*)(H + 12 * TCsz - 1572864 - 262144);  // 128*64*16 fp32 = 512 KB
  ushort_t* wqkv  = wb;
  ushort_t* wqkvs = wb + 196608;
  ushort_t* wproj = wb + 393216;
  ushort_t* wprojs= wb + 458752;
  ushort_t* wfc1  = wb + 524288;
  ushort_t* wfc1s = wb + 786432;
  ushort_t* wfc2  = wb + 1048576;
  ushort_t* wfc2s = wb + 1310720;

  // 0. convert weights + fragment bias table + V^T tail zero
  f2b_k<<<768, 256, 0, stream>>>(qkv_w,  wqkv,  196608);
  f2b_k<<<768, 256, 0, stream>>>(qkvs_w, wqkvs, 196608);
  f2b_k<<<256, 256, 0, stream>>>(proj_w, wproj, 65536);
  f2b_k<<<256, 256, 0, stream>>>(projs_w,wprojs,65536);
  f2b_k<<<1024,256, 0, stream>>>(fc1_w,  wfc1,  262144);
  f2b_k<<<1024,256, 0, stream>>>(fc1s_w, wfc1s, 262144);
  f2b_k<<<1024,256, 0, stream>>>(fc2_w,  wfc2,  262144);
  f2b_k<<<1024,256, 0, stream>>>(fc2s_w, wfc2s, 262144);
  bias2_k<<<128, 64, 0, stream>>>(rpb, biasf);
  vtz_k<<<2048, 256, 0, stream>>>(vtA, vtB);

  // 1. LN1 + shift + window partition (bf16 out)
  ln_k<1><<<12544, 256, 0, stream>>>(x,    ln1_g,  ln1_b,  xw);
  ln_k<1><<<12544, 256, 0, stream>>>(xsar, ln1s_g, ln1s_b, xws);
  // 2. QKV MFMA GEMM (q pre-scaled); q,k -> [pair][n][d], V -> [pair][d][64]
  bgemm_k<0><<<dim3(6, 392), 256, 0, stream>>>(xw,  wqkv,  qkv_b,  (float*)vtA, q,  nullptr, 256, 768);
  bgemm_k<0><<<dim3(6, 392), 256, 0, stream>>>(xws, wqkvs, qkvs_b, (float*)vtB, qs, nullptr, 256, 768);
  // 3. fused attention (scores + gate + softmax + PV), both branches
  attn_k<<<4096, 256, 0, stream>>>(q, qs, vtA, vtB, biasf, fuse_w, fuse_b, H);
  // 4. proj MFMA + window-reverse + roll(+3) + residual -> fp32 xr
  bgemm_k<1><<<dim3(2, 392), 256, 0, stream>>>(H,        wproj,  proj_b,  xr,  nullptr, x,    256, 256);
  bgemm_k<1><<<dim3(2, 392), 256, 0, stream>>>(H + TCsz, wprojs, projs_b, xrs, nullptr, xsar, 256, 256);
  // 5. LN2 (bf16 out)
  ln_k<0><<<12544, 256, 0, stream>>>(xr,  ln2_g,  ln2_b,  y);
  ln_k<0><<<12544, 256, 0, stream>>>(xrs, ln2s_g, ln2s_b, ysb);
  // 6. MLP (MFMA)
  bgemm_k<2><<<dim3(8, 392), 256, 0, stream>>>(y,    wfc1,  fc1_b,  nullptr, hbuf, nullptr, 256, 1024);
  bgemm_k<3><<<dim3(2, 392), 256, 0, stream>>>(hbuf, wfc2,  fc2_b,  out,     nullptr, xr,  1024, 256);
  bgemm_k<2><<<dim3(8, 392), 256, 0, stream>>>(ysb,  wfc1s, fc1s_b, nullptr, hbuf, nullptr, 256, 1024);
  bgemm_k<3><<<dim3(2, 392), 256, 0, stream>>>(hbuf, wfc2s, fc2s_b, out + TCsz, nullptr, xrs, 1024, 256);
}